// Round 1
// baseline (391.275 us; speedup 1.0000x reference)
//
#include <hip/hip_runtime.h>
#include <stdint.h>

typedef unsigned int  u32;
typedef unsigned short u16;

#define B_ROWS 131072
#define P_PRED 64
#define C_CLS  128
#define NPAIR  384               // C*L raw words for dtype detection
#define CAP    32                // max records per predicate (mean 6)
#define RPB    128               // rows per block (2 rows per thread)
#define TPB    512               // 8 waves; wave g owns predicates [8g, 8g+8)
#define GCAP   104               // record capacity per 8-pred group (mean 48)
#define LOG2E  1.4426950408889634f

#if __has_builtin(__builtin_amdgcn_exp2f)
#define EXP2F(x) __builtin_amdgcn_exp2f(x)
#else
#define EXP2F(x) exp2f(x)
#endif

#if __has_builtin(__builtin_amdgcn_rcpf)
#define RCPF(x) __builtin_amdgcn_rcpf(x)
#else
#define RCPF(x) (1.0f / (x))
#endif

__device__ __forceinline__ float bf16_to_f(u16 u) {
    return __uint_as_float(((u32)u) << 16);
}
__device__ __forceinline__ u16 f_to_bf16(float f) {
    u32 u = __float_as_uint(f);
    u += 0x7FFFu + ((u >> 16) & 1u);   // RNE
    return (u16)(u >> 16);
}
__device__ __forceinline__ u32 pack_bf16x2(float lo, float hi) {
    return (u32)f_to_bf16(lo) | ((u32)f_to_bf16(hi) << 16);
}

// ---------------------------------------------------------------------------
// DIAGNOSTIC ROUND (R11): rep-amplified, bit-identical variants of the R9/R10
// fused kernel so ke_fused's counters become visible in the top-5 table
// (baseline ke_fused is <41.7us and hidden behind the 42us harness fills).
//   ke_probe<8,1>: full body x8  -> dispatch ~ 8*t_full  (aggregate counters)
//   ke_probe<1,8>: record loop x8 -> dispatch ~ t_full + 7*t_rec (isolates
//                  the record phase; asm keep-alive + "memory" clobber per
//                  rep prevents DCE/CSE of the repeated work, rule 17/18)
// Every rep recomputes and rewrites the IDENTICAL output -> passed unchanged.
// Kernel logic is byte-for-byte the R9-validated structure; only the two rep
// loops and the trailing barrier (S-reuse guard between full reps) are new.
// ---------------------------------------------------------------------------
template<int RFULL, int RREC>
__global__ __launch_bounds__(TPB, 8)
void ke_probe(const u32* __restrict__ lidx_w,
              const u32* __restrict__ sb_w,
              const u32* __restrict__ w_w,
              const void* __restrict__ atoms_v,
              void* __restrict__ out_v) {
    __shared__ u32 S[8192];                   // 32 KB: prep scratch, then E2
    __shared__ uint2 srec[8 * GCAP];          // 6656 B (persists all phases)
    __shared__ unsigned char cnt8[P_PRED];    // 64 B
    u16* E2 = (u16*)S;                        // [slot][128 rows] bf16

    const int tid = threadIdx.x;
    const int lane = tid & 63;
    const int g = __builtin_amdgcn_readfirstlane(tid >> 6);  // 0..7, SGPR
    const int rowBase = blockIdx.x * RPB;

    for (int frep = 0; frep < RFULL; ++frep) {

    // ======== phase 0: inline prep (scratch aliased into S) ========
    int*   scnt  = (int*)&S[0];       // [64]
    int*   det   = (int*)&S[64];      // [3]
    int*   sidx  = (int*)&S[128];     // [384]
    int*   ssb   = (int*)&S[512];     // [384]
    u32*   recPk = &S[1024];          // [64][32]
    float* recW  = (float*)&S[3072];  // [64][32]

    if (tid < P_PRED) scnt[tid] = 0;
    if (tid < 3) det[tid] = 1;
    __syncthreads();
    if (tid < NPAIR / 2) {
        if (lidx_w[2 * tid + 1] != 0u) det[0] = 0;   // benign race (all write 0)
        if (sb_w[2 * tid + 1]   != 0u) det[1] = 0;
    }
    if (tid == 0 && (w_w[0] & 0xFFFFu) == 0u) det[2] = 0;
    __syncthreads();
    if (tid < NPAIR) {
        sidx[tid] = (int)(det[0] ? lidx_w[2 * tid] : lidx_w[tid]);
        ssb[tid]  = (int)(det[1] ? sb_w[2 * tid]   : sb_w[tid]);
    }
    __syncthreads();
    const bool bf16m = (det[2] != 0);            // latch before S is reused
    if (tid < NPAIR) {
        const int c = tid / 3;
        const int l = tid - c * 3;
        const int base = c * 3;
        const int o1 = base + (l == 0 ? 1 : 0);
        const int o2 = base + (l == 2 ? 1 : 2);
        const int p = sidx[tid];
        const int slot = atomicAdd(&scnt[p], 1); // prep-only LDS atomics: fine
        float wraw = bf16m ? bf16_to_f((u16)(w_w[c / 2] >> ((c & 1) * 16)))
                           : __uint_as_float(w_w[c]);
        float wc = fminf(fmaxf(wraw, 0.0f), 500.0f);
        if (slot < CAP) {
            u32 s1 = 2u * (u32)sidx[o1] + (ssb[o1] ? 0u : 1u);
            u32 s2 = 2u * (u32)sidx[o2] + (ssb[o2] ? 0u : 1u);
            recPk[p * CAP + slot] = (ssb[tid] ? 0u : 1u) | (s1 << 8) | (s2 << 16);
            recW[p * CAP + slot]  = ssb[tid] ? wc : -wc;
        }
    }
    __syncthreads();
    if (tid < P_PRED) {
        const int p = tid;
        const int gg = p >> 3;
        const int n = min(scnt[p], CAP);
        int off = 0;
        for (int pb = gg * 8; pb < p; ++pb) off += min(scnt[pb], CAP);
        int ncl = 0;
        for (int j = 0; j < n; ++j) {
            if (off + j < GCAP) {
                srec[gg * GCAP + off + j] =
                    make_uint2(recPk[p * CAP + j], __float_as_uint(recW[p * CAP + j]));
                ++ncl;
            }
        }
        cnt8[p] = (unsigned char)ncl;
    }
    __syncthreads();   // srec/cnt8 ready; prep scratch in S now dead

    // ======== phase 1: stage E2 (paired-row b32 writes) ========
    {
        const int a = tid & 63;                  // row pair (2a, 2a+1)
        const int c0 = (tid >> 6) * 8;           // 8-atom chunk
        if (bf16m) {
            const u16* gp0 = (const u16*)atoms_v + (size_t)(rowBase + 2 * a) * P_PRED + c0;
            uint4 v0 = *(const uint4*)gp0;            // row 2a
            uint4 v1 = *(const uint4*)(gp0 + P_PRED); // row 2a+1
            u32 w0[4] = {v0.x, v0.y, v0.z, v0.w};
            u32 w1[4] = {v1.x, v1.y, v1.z, v1.w};
#pragma unroll
            for (int k = 0; k < 4; ++k) {
                float xl0 = __uint_as_float(w0[k] << 16) * LOG2E;
                float xh0 = __uint_as_float(w0[k] & 0xFFFF0000u) * LOG2E;
                float xl1 = __uint_as_float(w1[k] << 16) * LOG2E;
                float xh1 = __uint_as_float(w1[k] & 0xFFFF0000u) * LOG2E;
                float el0 = EXP2F(xl0), eh0 = EXP2F(xh0);
                float el1 = EXP2F(xl1), eh1 = EXP2F(xh1);
                const int m = c0 + 2 * k;
                S[(2 * m)     * 64 + a] = pack_bf16x2(el0, el1);
                S[(2 * m + 1) * 64 + a] = pack_bf16x2(RCPF(el0), RCPF(el1));
                S[(2 * m + 2) * 64 + a] = pack_bf16x2(eh0, eh1);
                S[(2 * m + 3) * 64 + a] = pack_bf16x2(RCPF(eh0), RCPF(eh1));
            }
        } else {
            const float* gp0 = (const float*)atoms_v + (size_t)(rowBase + 2 * a) * P_PRED + c0;
            float4 u0 = *(const float4*)gp0;
            float4 u1 = *(const float4*)(gp0 + 4);
            float4 d0 = *(const float4*)(gp0 + P_PRED);
            float4 d1 = *(const float4*)(gp0 + P_PRED + 4);
            float r0[8] = {u0.x, u0.y, u0.z, u0.w, u1.x, u1.y, u1.z, u1.w};
            float r1[8] = {d0.x, d0.y, d0.z, d0.w, d1.x, d1.y, d1.z, d1.w};
#pragma unroll
            for (int k = 0; k < 8; ++k) {
                float e0 = EXP2F(r0[k] * LOG2E);
                float e1 = EXP2F(r1[k] * LOG2E);
                const int m = c0 + k;
                S[(2 * m)     * 64 + a] = pack_bf16x2(e0, e1);
                S[(2 * m + 1) * 64 + a] = pack_bf16x2(RCPF(e0), RCPF(e1));
            }
        }
    }
    __syncthreads();

    // ======== phase 2: record loop (rep-amplified in ke_probe<1,8>) ========
    const int q2 = 2 * lane;               // u16 row index of this row pair
    float2 acc[8];

    for (int rrep = 0; rrep < RREC; ++rrep) {
        int j = g * GCAP;                  // stream cursor (reset per rep)

#pragma unroll
        for (int pp = 0; pp < 8; ++pp) {
            const int p = g * 8 + pp;                        // wave-uniform
            const u32 eppv = *(const u32*)&E2[(2 * p)     * RPB + q2];
            const u32 epnv = *(const u32*)&E2[(2 * p + 1) * RPB + q2];
            const float eppx = __uint_as_float(eppv << 16);
            const float eppy = __uint_as_float(eppv & 0xFFFF0000u);
            const float epnx = __uint_as_float(epnv << 16);
            const float epny = __uint_as_float(epnv & 0xFFFF0000u);
            const int n = (int)cnt8[p];
            float2 a0 = make_float2(0.0f, 0.0f);
            float2 a1 = make_float2(0.0f, 0.0f);

#define REC_BODY(J, A)                                                        \
            {                                                                 \
                const uint2 rec = srec[J];                 /* b64 broadcast */\
                const u32 pk = rec.x;                                         \
                const float sw = __uint_as_float(rec.y);                      \
                const u32 s1v = *(const u32*)&E2[(int)((pk >> 8)  & 255u) * RPB + q2]; \
                const u32 s2v = *(const u32*)&E2[(int)((pk >> 16) & 255u) * RPB + q2]; \
                const float ssx = (pk & 1u) ? epnx : eppx;                    \
                const float ssy = (pk & 1u) ? epny : eppy;                    \
                const float s1x = __uint_as_float(s1v << 16);                 \
                const float s1y = __uint_as_float(s1v & 0xFFFF0000u);         \
                const float s2x = __uint_as_float(s2v << 16);                 \
                const float s2y = __uint_as_float(s2v & 0xFFFF0000u);         \
                const float tx = RCPF(ssx + s1x + s2x);                       \
                const float ty = RCPF(ssy + s1y + s2y);                       \
                A.x = fmaf(sw * ssx, tx, A.x);                                \
                A.y = fmaf(sw * ssy, ty, A.y);                                \
            }

            int e = 0;
            for (; e + 3 < n; e += 4) {        // unroll x4, dual accumulators
                REC_BODY(j,     a0)
                REC_BODY(j + 1, a1)
                REC_BODY(j + 2, a0)
                REC_BODY(j + 3, a1)
                j += 4;
            }
            for (; e < n; ++e, ++j) REC_BODY(j, a0)
#undef REC_BODY
            acc[pp] = make_float2(a0.x + a1.x, a0.y + a1.y);
        }

        // Keep each rep's results live and force LDS re-reads next rep
        // (rule 17: skip-ablation DCE; "memory" defeats cross-rep CSE).
        asm volatile("" : "+v"(acc[0].x), "+v"(acc[0].y), "+v"(acc[1].x), "+v"(acc[1].y),
                          "+v"(acc[2].x), "+v"(acc[2].y), "+v"(acc[3].x), "+v"(acc[3].y),
                          "+v"(acc[4].x), "+v"(acc[4].y), "+v"(acc[5].x), "+v"(acc[5].y),
                          "+v"(acc[6].x), "+v"(acc[6].y), "+v"(acc[7].x), "+v"(acc[7].y)
                     :: "memory");
    }

    // ======== phase 3: direct stores (R9 epilogue) ========
    if (bf16m) {
        u16* op0 = (u16*)out_v + (size_t)(rowBase + q2) * P_PRED + g * 8;
        u16* op1 = op0 + P_PRED;
        uint4 o0, o1v;
        o0.x  = pack_bf16x2(acc[0].x, acc[1].x);
        o0.y  = pack_bf16x2(acc[2].x, acc[3].x);
        o0.z  = pack_bf16x2(acc[4].x, acc[5].x);
        o0.w  = pack_bf16x2(acc[6].x, acc[7].x);
        o1v.x = pack_bf16x2(acc[0].y, acc[1].y);
        o1v.y = pack_bf16x2(acc[2].y, acc[3].y);
        o1v.z = pack_bf16x2(acc[4].y, acc[5].y);
        o1v.w = pack_bf16x2(acc[6].y, acc[7].y);
        *(uint4*)op0 = o0;
        *(uint4*)op1 = o1v;
    } else {
        float* op0 = (float*)out_v + (size_t)(rowBase + q2) * P_PRED + g * 8;
        float* op1 = op0 + P_PRED;
        *(float4*)(op0)     = make_float4(acc[0].x, acc[1].x, acc[2].x, acc[3].x);
        *(float4*)(op0 + 4) = make_float4(acc[4].x, acc[5].x, acc[6].x, acc[7].x);
        *(float4*)(op1)     = make_float4(acc[0].y, acc[1].y, acc[2].y, acc[3].y);
        *(float4*)(op1 + 4) = make_float4(acc[4].y, acc[5].y, acc[6].y, acc[7].y);
    }

    __syncthreads();   // guard S reuse by next full rep's phase-0 init
    }                  // frep
}

extern "C" void kernel_launch(void* const* d_in, const int* in_sizes, int n_in,
                              void* d_out, int out_size, void* d_ws, size_t ws_size,
                              hipStream_t stream_h) {
    const u32* clause_weights = (const u32*)d_in[1]; // bf16 or f32 [128]
    const u32* literal_idx    = (const u32*)d_in[2]; // int32 or int64 [128,3]
    const u32* sign_bits      = (const u32*)d_in[3]; // int32 or int64 [128,3]
    (void)d_ws; (void)ws_size;                       // workspace unused

    // d1: full body x8 -> ~8*t_full, rank-1 dispatch with full counters
    hipLaunchKernelGGL(HIP_KERNEL_NAME(ke_probe<8, 1>),
                       dim3(B_ROWS / RPB), dim3(TPB), 0, stream_h,
                       literal_idx, sign_bits, clause_weights, d_in[0], d_out);
    // d2: record phase x8 -> t_full + 7*t_rec, isolates the record loop
    hipLaunchKernelGGL(HIP_KERNEL_NAME(ke_probe<1, 8>),
                       dim3(B_ROWS / RPB), dim3(TPB), 0, stream_h,
                       literal_idx, sign_bits, clause_weights, d_in[0], d_out);
}

// Round 2
// 341.025 us; speedup vs baseline: 1.1474x; 1.1474x over previous
//
#include <hip/hip_runtime.h>
#include <stdint.h>

typedef unsigned int  u32;
typedef unsigned short u16;

#define B_ROWS 131072
#define P_PRED 64
#define C_CLS  128
#define NPAIR  384               // C*L raw words for dtype detection
#define RPB    128               // rows per block (2 rows per thread-lane)
#define TPB    1024              // 16 waves; wave g owns clauses [8g, 8g+8)
#define LOG2E  1.4426950408889634f

#if __has_builtin(__builtin_amdgcn_exp2f)
#define EXP2F(x) __builtin_amdgcn_exp2f(x)
#else
#define EXP2F(x) exp2f(x)
#endif

#if __has_builtin(__builtin_amdgcn_rcpf)
#define RCPF(x) __builtin_amdgcn_rcpf(x)
#else
#define RCPF(x) (1.0f / (x))
#endif

__device__ __forceinline__ float bf16_to_f(u16 u) {
    return __uint_as_float(((u32)u) << 16);
}
__device__ __forceinline__ u16 f_to_bf16(float f) {
    u32 u = __float_as_uint(f);
    u += 0x7FFFu + ((u >> 16) & 1u);   // RNE
    return (u16)(u >> 16);
}
__device__ __forceinline__ u32 pack_bf16x2(float lo, float hi) {
    return (u32)f_to_bf16(lo) | ((u32)f_to_bf16(hi) << 16);
}
__device__ __forceinline__ void LADD(float* p, float v) {
    // LDS f32 add, no return -> ds_add_f32 (fire-and-forget)
    __hip_atomic_fetch_add(p, v, __ATOMIC_RELAXED, __HIP_MEMORY_SCOPE_WORKGROUP);
}

// ---------------------------------------------------------------------------
// R12: CLAUSE-MAJOR rewrite (probe-driven: record loop was ~100% of kernel,
// VALU-bound at 71% with VGPR=32).
//   - Each clause's softmax denominator + rcp computed ONCE (was 3x as
//     predicate-major records): per clause/row-pair ~28 VALU + 2 rcp vs
//     ~132 + 6 rcp before.
//   - Clause metadata latched to SGPRs via readfirstlane ONCE per block
//     (24 ops, not R9's per-record readlane) -> decode/sign/addr-base on
//     the free SALU pipe.
//   - Scatter via ds_add_f32 into a 32KB LDS f32 accumulator [pred][row];
//     stride-2 bank pattern (~free, m136); no VGPR acc arrays needed.
//   - Readout phase gives PERFECTLY coalesced stores (fixes the measured
//     2.4x WRITE_SIZE inflation + RMW fetch of the 16B/256B store pattern).
// LDS = 32KB E2 + 32KB acc = 64KB static -> 2 blocks/CU x 16 waves = 32
// waves/CU (100%); __launch_bounds__(1024,8) pins VGPR<=64.
// Workspace d_ws: UNUSED.
// ---------------------------------------------------------------------------
__global__ __launch_bounds__(TPB, 8)
void ke_clause(const u32* __restrict__ lidx_w,
               const u32* __restrict__ sb_w,
               const u32* __restrict__ w_w,
               const void* __restrict__ atoms_v,
               void* __restrict__ out_v) {
    __shared__ u32 SS[8192];              // 32 KB: prep scratch, then E2
    __shared__ float ACC[P_PRED * RPB];   // 32 KB: f32 accumulators [p][row]
    u16* E2 = (u16*)SS;                   // [128 slots][128 rows] bf16

    const int tid = threadIdx.x;
    const int lane = tid & 63;
    const int g2 = tid >> 6;              // wave id 0..15
    const int rowBase = blockIdx.x * RPB;

    // prep scratch aliased into SS (dead before E2 staging)
    int* det  = (int*)&SS[0];     // [3]
    int* sidx = (int*)&SS[4];     // [384]
    int* ssb  = (int*)&SS[388];   // [384]
    u32* cm   = &SS[1024];        // uint4[128] clause metadata (u32[512])

    // ======== phase 0a: zero ACC + dtype detect ========
#pragma unroll
    for (int i = tid; i < P_PRED * RPB; i += TPB) ACC[i] = 0.0f;
    if (tid < 3) det[tid] = 1;
    __syncthreads();
    if (tid < NPAIR / 2) {
        if (lidx_w[2 * tid + 1] != 0u) det[0] = 0;   // benign race (all write 0)
        if (sb_w[2 * tid + 1]   != 0u) det[1] = 0;
    }
    if (tid == 0 && (w_w[0] & 0xFFFFu) == 0u) det[2] = 0;
    __syncthreads();
    if (tid < NPAIR) {
        sidx[tid] = (int)(det[0] ? lidx_w[2 * tid] : lidx_w[tid]);
        ssb[tid]  = (int)(det[1] ? sb_w[2 * tid]   : sb_w[tid]);
    }
    __syncthreads();
    const bool bf16m = (det[2] != 0);     // latch before SS is reused

    // ======== phase 0b: clause metadata (one thread per clause) ========
    if (tid < C_CLS) {
        const int c = tid;
        const int i0 = sidx[3 * c], i1 = sidx[3 * c + 1], i2 = sidx[3 * c + 2];
        const u32 n0 = ssb[3 * c]     ? 0u : 1u;     // negate bits
        const u32 n1 = ssb[3 * c + 1] ? 0u : 1u;
        const u32 n2 = ssb[3 * c + 2] ? 0u : 1u;
        const u32 s0 = 2u * (u32)i0 + n0;            // E2 slot = 2*atom + neg
        const u32 s1 = 2u * (u32)i1 + n1;
        const u32 s2 = 2u * (u32)i2 + n2;
        float wraw = bf16m ? bf16_to_f((u16)(w_w[c >> 1] >> ((c & 1) * 16)))
                           : __uint_as_float(w_w[c]);
        float wc = fminf(fmaxf(wraw, 0.0f), 500.0f);
        cm[4 * c + 0] = s0 | (s1 << 8) | (s2 << 16) | (n0 << 24) | (n1 << 25) | (n2 << 26);
        cm[4 * c + 1] = (u32)i0 | ((u32)i1 << 8) | ((u32)i2 << 16);
        cm[4 * c + 2] = __float_as_uint(wc);
        cm[4 * c + 3] = 0u;
    }
    __syncthreads();

    // ======== phase 0c: latch this wave's 8 clauses into SGPRs ========
    u32 smx[8], smy[8], swb[8];
#pragma unroll
    for (int cc = 0; cc < 8; ++cc) {
        const uint4 mm = *(const uint4*)&cm[4 * (g2 * 8 + cc)];  // b128 broadcast
        smx[cc] = __builtin_amdgcn_readfirstlane(mm.x);
        smy[cc] = __builtin_amdgcn_readfirstlane(mm.y);
        swb[cc] = __builtin_amdgcn_readfirstlane(mm.z);
    }
    __syncthreads();   // metadata in SGPRs; prep scratch in SS now dead

    // ======== phase 1: stage E2 (paired-row b32 writes) ========
    {
        const int a = lane;                      // row pair (2a, 2a+1)
        const int c0 = g2 * 4;                   // 4-atom chunk (16 waves x 4)
        if (bf16m) {
            const u16* gp0 = (const u16*)atoms_v + (size_t)(rowBase + 2 * a) * P_PRED + c0;
            uint2 v0 = *(const uint2*)gp0;            // row 2a, atoms c0..c0+3
            uint2 v1 = *(const uint2*)(gp0 + P_PRED); // row 2a+1
            u32 w0[2] = {v0.x, v0.y};
            u32 w1[2] = {v1.x, v1.y};
#pragma unroll
            for (int k = 0; k < 2; ++k) {
                float xl0 = __uint_as_float(w0[k] << 16) * LOG2E;
                float xh0 = __uint_as_float(w0[k] & 0xFFFF0000u) * LOG2E;
                float xl1 = __uint_as_float(w1[k] << 16) * LOG2E;
                float xh1 = __uint_as_float(w1[k] & 0xFFFF0000u) * LOG2E;
                float el0 = EXP2F(xl0), eh0 = EXP2F(xh0);
                float el1 = EXP2F(xl1), eh1 = EXP2F(xh1);
                const int m = c0 + 2 * k;
                SS[(2 * m)     * 64 + a] = pack_bf16x2(el0, el1);
                SS[(2 * m + 1) * 64 + a] = pack_bf16x2(RCPF(el0), RCPF(el1));
                SS[(2 * m + 2) * 64 + a] = pack_bf16x2(eh0, eh1);
                SS[(2 * m + 3) * 64 + a] = pack_bf16x2(RCPF(eh0), RCPF(eh1));
            }
        } else {
            const float* gp0 = (const float*)atoms_v + (size_t)(rowBase + 2 * a) * P_PRED + c0;
            float4 u0 = *(const float4*)gp0;             // row 2a
            float4 d0 = *(const float4*)(gp0 + P_PRED);  // row 2a+1
            float r0[4] = {u0.x, u0.y, u0.z, u0.w};
            float r1[4] = {d0.x, d0.y, d0.z, d0.w};
#pragma unroll
            for (int k = 0; k < 4; ++k) {
                float e0 = EXP2F(r0[k] * LOG2E);
                float e1 = EXP2F(r1[k] * LOG2E);
                const int m = c0 + k;
                SS[(2 * m)     * 64 + a] = pack_bf16x2(e0, e1);
                SS[(2 * m + 1) * 64 + a] = pack_bf16x2(RCPF(e0), RCPF(e1));
            }
        }
    }
    __syncthreads();

    // ======== phase 2: clause loop (8 clauses/wave, SGPR metadata) ========
    {
        const int laneB = lane * 4;              // byte offset into an E2 slot row
        const int rcol  = 2 * lane;              // acc column (row index)
#pragma unroll
        for (int cc = 0; cc < 8; ++cc) {
            const u32 mx = smx[cc], my = smy[cc], wb = swb[cc];
            // SALU: slot byte-offsets; VALU: single add with laneB
            const u32 v1 = *(const u32*)((const char*)E2 + (((mx      ) & 255u) << 8) + laneB);
            const u32 v2 = *(const u32*)((const char*)E2 + (((mx >>  8) & 255u) << 8) + laneB);
            const u32 v3 = *(const u32*)((const char*)E2 + (((mx >> 16) & 255u) << 8) + laneB);
            const float e1x = __uint_as_float(v1 << 16), e1y = __uint_as_float(v1 & 0xFFFF0000u);
            const float e2x = __uint_as_float(v2 << 16), e2y = __uint_as_float(v2 & 0xFFFF0000u);
            const float e3x = __uint_as_float(v3 << 16), e3y = __uint_as_float(v3 & 0xFFFF0000u);
            const float rx = RCPF(e1x + e2x + e3x);      // ONE denom+rcp per clause/row
            const float ry = RCPF(e1y + e2y + e3y);
            const float w0 = __uint_as_float(wb | (((mx >> 24) & 1u) << 31));  // SALU
            const float w1 = __uint_as_float(wb | (((mx >> 25) & 1u) << 31));
            const float w2 = __uint_as_float(wb | (((mx >> 26) & 1u) << 31));
            float* a0 = &ACC[(int)((my      ) & 255u) * RPB + rcol];
            float* a1 = &ACC[(int)((my >>  8) & 255u) * RPB + rcol];
            float* a2 = &ACC[(int)((my >> 16) & 255u) * RPB + rcol];
            LADD(a0,     w0 * (e1x * rx));
            LADD(a0 + 1, w0 * (e1y * ry));
            LADD(a1,     w1 * (e2x * rx));
            LADD(a1 + 1, w1 * (e2y * ry));
            LADD(a2,     w2 * (e3x * rx));
            LADD(a2 + 1, w2 * (e3y * ry));
        }
    }
    __syncthreads();

    // ======== phase 3: readout — fully coalesced stores ========
    {
        const int row = tid >> 3;                // 0..127
        const int pg  = tid & 7;                 // pred octet
        float v[8];
#pragma unroll
        for (int k = 0; k < 8; ++k) v[k] = ACC[(pg * 8 + k) * RPB + row];
        if (bf16m) {
            uint4 o;
            o.x = pack_bf16x2(v[0], v[1]);
            o.y = pack_bf16x2(v[2], v[3]);
            o.z = pack_bf16x2(v[4], v[5]);
            o.w = pack_bf16x2(v[6], v[7]);
            *(uint4*)((u16*)out_v + (size_t)(rowBase + row) * P_PRED + pg * 8) = o;
        } else {
            float* op = (float*)out_v + (size_t)(rowBase + row) * P_PRED + pg * 8;
            *(float4*)op       = make_float4(v[0], v[1], v[2], v[3]);
            *(float4*)(op + 4) = make_float4(v[4], v[5], v[6], v[7]);
        }
    }
}

extern "C" void kernel_launch(void* const* d_in, const int* in_sizes, int n_in,
                              void* d_out, int out_size, void* d_ws, size_t ws_size,
                              hipStream_t stream_h) {
    const u32* clause_weights = (const u32*)d_in[1]; // bf16 or f32 [128]
    const u32* literal_idx    = (const u32*)d_in[2]; // int32 or int64 [128,3]
    const u32* sign_bits      = (const u32*)d_in[3]; // int32 or int64 [128,3]
    (void)d_ws; (void)ws_size;                       // workspace unused

    ke_clause<<<B_ROWS / RPB, TPB, 0, stream_h>>>(literal_idx, sign_bits,
                                                  clause_weights, d_in[0],
                                                  d_out);
}

// Round 3
// 124.390 us; speedup vs baseline: 3.1455x; 2.7416x over previous
//
#include <hip/hip_runtime.h>
#include <stdint.h>

typedef unsigned int  u32;
typedef unsigned short u16;

#define B_ROWS 131072
#define P_PRED 64
#define C_CLS  128
#define NPAIR  384               // C*L raw words for dtype detection
#define RPB    128               // rows per block (2 rows per thread-lane)
#define TPB    512               // 8 waves; wave g owns predicates [8g, 8g+8)
#define GCAP   104               // record capacity per 8-pred group (R9-proven)
#define CAPH   24                // per (pred, clause-quarter) scratch cap (mean 1.5)
#define NRND   4                 // clause quarters (rounds)
#define CPR    32                // clauses per round
#define LOG2E  1.4426950408889634f

#if __has_builtin(__builtin_amdgcn_exp2f)
#define EXP2F(x) __builtin_amdgcn_exp2f(x)
#else
#define EXP2F(x) exp2f(x)
#endif

#if __has_builtin(__builtin_amdgcn_rcpf)
#define RCPF(x) __builtin_amdgcn_rcpf(x)
#else
#define RCPF(x) (1.0f / (x))
#endif

__device__ __forceinline__ float bf16_to_f(u16 u) {
    return __uint_as_float(((u32)u) << 16);
}
__device__ __forceinline__ u16 f_to_bf16(float f) {
    u32 u = __float_as_uint(f);
    u += 0x7FFFu + ((u >> 16) & 1u);   // RNE
    return (u16)(u >> 16);
}
__device__ __forceinline__ u32 pack_bf16x2(float lo, float hi) {
    return (u32)f_to_bf16(lo) | ((u32)f_to_bf16(hi) << 16);
}

// ---------------------------------------------------------------------------
// R13: R9 CSR skeleton + per-clause w/D precompute (NO atomics — R12's
// ds_add_f32 scatter was the 10x poison, VALUBusy 4%).
//   - WR pre-pass (per round of 32 clauses): wrd[c][row] = clamp(w)/D f32 in
//     16 KB LDS; computed ONCE per clause (was 3x per record in R9).
//   - Record loop: broadcast rec -> readfirstlane -> SALU decode; 1 E2 read
//     + 1 ds_read_b64 (wrd pair) + sign-XOR + 2 fma. ~9 VALU, 0 rcp/record
//     (R9: ~22 VALU + 2 rcp).
//   - 4 rounds (WR overwritten); prep partitions each pred's stream by
//     clause-quarter; same GCAP=104 group capacity as passing R9.
// LDS = 32K(E2) + 16K(WR) + 3.3K(srec) + 1.5K(meta) = 54.0 KB
//   -> 3 blocks/CU x 8 waves = 24 waves/CU.
// Workspace d_ws: UNUSED.
// ---------------------------------------------------------------------------
__global__ __launch_bounds__(TPB, 6)
void ke_wr(const u32* __restrict__ lidx_w,
           const u32* __restrict__ sb_w,
           const u32* __restrict__ w_w,
           const void* __restrict__ atoms_v,
           void* __restrict__ out_v) {
    __shared__ u32 S[8192];                       // 32 KB: prep scratch, then E2
    __shared__ float WRF[CPR * RPB];              // 16 KB: w/D f32 [c&31][row]
    __shared__ u32 srec32[8 * GCAP];              // 3328 B record streams
    __shared__ unsigned char cnth[NRND][P_PRED];  // 256 B stored counts
    __shared__ unsigned char poff[NRND][P_PRED];  // 256 B stream offsets
    __shared__ u32 cslot[C_CLS];                  // 512 B clause slot triples
    __shared__ float cwv[C_CLS];                  // 512 B clamped weights

    const int tid  = threadIdx.x;
    const int lane = tid & 63;
    const int g    = __builtin_amdgcn_readfirstlane(tid >> 6);  // wave 0..7
    const int rowBase = blockIdx.x * RPB;

    // prep scratch aliased into S (dead before E2 staging)
    int* scnt4 = (int*)&S[0];       // [256]  (pred*4 + quarter)
    int* det   = (int*)&S[256];     // [3]
    int* sidx  = (int*)&S[260];     // [384]
    int* ssb   = (int*)&S[644];     // [384]
    u32* recQ  = &S[1032];          // [64*4*CAPH = 6144]

    // ======== phase 0a: init + dtype detect ========
    if (tid < 256) scnt4[tid] = 0;
    if (tid < 3) det[tid] = 1;
    __syncthreads();
    if (tid < NPAIR / 2) {
        if (lidx_w[2 * tid + 1] != 0u) det[0] = 0;   // benign race (all write 0)
        if (sb_w[2 * tid + 1]   != 0u) det[1] = 0;
    }
    if (tid == 0 && (w_w[0] & 0xFFFFu) == 0u) det[2] = 0;
    __syncthreads();
    if (tid < NPAIR) {
        sidx[tid] = (int)(det[0] ? lidx_w[2 * tid] : lidx_w[tid]);
        ssb[tid]  = (int)(det[1] ? sb_w[2 * tid]   : sb_w[tid]);
    }
    __syncthreads();
    const bool bf16m = (det[2] != 0);     // latch before S is reused

    // ======== phase 0b: record insert (by quarter) + clause meta ========
    if (tid < NPAIR) {
        const int c = tid / 3;
        const int p = sidx[tid];
        const int h = c >> 5;                          // clause quarter 0..3
        const int slot = atomicAdd(&scnt4[p * 4 + h], 1);   // int LDS atomic: fine
        const u32 ss = 2u * (u32)p + (ssb[tid] ? 0u : 1u);  // E2 slot (bit0 = neg)
        if (slot < CAPH)
            recQ[(p * 4 + h) * CAPH + slot] =
                (ss << 8) | ((u32)((c & 31) << 9) << 16);   // lo: E2 byte-off base; hi: WR byte-off base
    }
    if (tid < C_CLS) {
        const int c = tid;
        const u32 s0 = 2u * (u32)sidx[3 * c]     + (ssb[3 * c]     ? 0u : 1u);
        const u32 s1 = 2u * (u32)sidx[3 * c + 1] + (ssb[3 * c + 1] ? 0u : 1u);
        const u32 s2 = 2u * (u32)sidx[3 * c + 2] + (ssb[3 * c + 2] ? 0u : 1u);
        cslot[c] = s0 | (s1 << 8) | (s2 << 16);
        float wraw = bf16m ? bf16_to_f((u16)(w_w[c >> 1] >> ((c & 1) * 16)))
                           : __uint_as_float(w_w[c]);
        cwv[c] = fminf(fmaxf(wraw, 0.0f), 500.0f);
    }
    __syncthreads();

    // ======== phase 0c: CSR copy, quarter-partitioned (thread-per-pred) ====
    if (tid < P_PRED) {
        const int p = tid, gg = p >> 3, gb = gg * 8;
        int off = 0;                           // cursor within group stream
        for (int r = 0; r < NRND; ++r) {
            int offp = off;
            for (int pb = gb; pb < p; ++pb) offp += min(scnt4[pb * 4 + r], CAPH);
            const int n = min(scnt4[p * 4 + r], CAPH);
            int k = 0;
            for (int j2 = 0; j2 < n; ++j2) {
                const int pos = offp + j2;
                if (pos < GCAP) { srec32[gg * GCAP + pos] = recQ[(p * 4 + r) * CAPH + j2]; ++k; }
            }
            poff[r][p] = (unsigned char)min(offp, 255);
            cnth[r][p] = (unsigned char)k;
            for (int pb = gb; pb < gb + 8; ++pb) off += min(scnt4[pb * 4 + r], CAPH);
        }
    }
    __syncthreads();   // streams ready; prep scratch in S now dead

    // ======== phase 1: stage E2 (paired-row b32 writes; R9-verbatim) ========
    {
        const int a  = lane;                     // row pair (2a, 2a+1)
        const int c0 = g * 8;                    // 8-atom chunk per wave
        if (bf16m) {
            const u16* gp0 = (const u16*)atoms_v + (size_t)(rowBase + 2 * a) * P_PRED + c0;
            uint4 v0 = *(const uint4*)gp0;            // row 2a
            uint4 v1 = *(const uint4*)(gp0 + P_PRED); // row 2a+1
            u32 w0[4] = {v0.x, v0.y, v0.z, v0.w};
            u32 w1[4] = {v1.x, v1.y, v1.z, v1.w};
#pragma unroll
            for (int k = 0; k < 4; ++k) {
                float xl0 = __uint_as_float(w0[k] << 16) * LOG2E;
                float xh0 = __uint_as_float(w0[k] & 0xFFFF0000u) * LOG2E;
                float xl1 = __uint_as_float(w1[k] << 16) * LOG2E;
                float xh1 = __uint_as_float(w1[k] & 0xFFFF0000u) * LOG2E;
                float el0 = EXP2F(xl0), eh0 = EXP2F(xh0);
                float el1 = EXP2F(xl1), eh1 = EXP2F(xh1);
                const int m = c0 + 2 * k;
                S[(2 * m)     * 64 + a] = pack_bf16x2(el0, el1);
                S[(2 * m + 1) * 64 + a] = pack_bf16x2(RCPF(el0), RCPF(el1));
                S[(2 * m + 2) * 64 + a] = pack_bf16x2(eh0, eh1);
                S[(2 * m + 3) * 64 + a] = pack_bf16x2(RCPF(eh0), RCPF(eh1));
            }
        } else {
            const float* gp0 = (const float*)atoms_v + (size_t)(rowBase + 2 * a) * P_PRED + c0;
            float4 u0 = *(const float4*)gp0;
            float4 u1 = *(const float4*)(gp0 + 4);
            float4 d0 = *(const float4*)(gp0 + P_PRED);
            float4 d1 = *(const float4*)(gp0 + P_PRED + 4);
            float r0[8] = {u0.x, u0.y, u0.z, u0.w, u1.x, u1.y, u1.z, u1.w};
            float r1[8] = {d0.x, d0.y, d0.z, d0.w, d1.x, d1.y, d1.z, d1.w};
#pragma unroll
            for (int k = 0; k < 8; ++k) {
                float e0 = EXP2F(r0[k] * LOG2E);
                float e1 = EXP2F(r1[k] * LOG2E);
                const int m = c0 + k;
                S[(2 * m)     * 64 + a] = pack_bf16x2(e0, e1);
                S[(2 * m + 1) * 64 + a] = pack_bf16x2(RCPF(e0), RCPF(e1));
            }
        }
    }
    __syncthreads();

    // ======== phase 2: 4 rounds of { WR pre-pass ; record sub-loop } ======
    const int laneB  = lane * 4;     // byte off into an E2 slot row (bf16x2)
    const int laneB8 = lane * 8;     // byte off into a WR clause row (f32x2)
    const int q2 = 2 * lane;         // first row of this lane's pair
    float2 acc[8];
#pragma unroll
    for (int pp = 0; pp < 8; ++pp) acc[pp] = make_float2(0.0f, 0.0f);

    for (int r = 0; r < NRND; ++r) {
        // ---- WR pass: wave g computes clauses r*32 + g*4 + k ----
#pragma unroll
        for (int k = 0; k < 4; ++k) {
            const int c = r * CPR + g * 4 + k;
            const u32 sl   = __builtin_amdgcn_readfirstlane(cslot[c]);   // SGPR
            const float wS = __uint_as_float(
                __builtin_amdgcn_readfirstlane(__float_as_uint(cwv[c])));
            const int b0 = (int)(sl         & 255u) << 8;    // SALU slot bases
            const int b1 = (int)((sl >>  8) & 255u) << 8;
            const int b2 = (int)((sl >> 16) & 255u) << 8;
            const u32 e0 = *(const u32*)((const char*)S + b0 + laneB);
            const u32 e1 = *(const u32*)((const char*)S + b1 + laneB);
            const u32 e2 = *(const u32*)((const char*)S + b2 + laneB);
            const float dx = __uint_as_float(e0 << 16) + __uint_as_float(e1 << 16)
                           + __uint_as_float(e2 << 16);
            const float dy = __uint_as_float(e0 & 0xFFFF0000u)
                           + __uint_as_float(e1 & 0xFFFF0000u)
                           + __uint_as_float(e2 & 0xFFFF0000u);
            float2 wv2;
            wv2.x = wS * RCPF(dx);
            wv2.y = wS * RCPF(dy);
            *(float2*)((char*)WRF + ((c & 31) << 9) + laneB8) = wv2;
        }
        __syncthreads();

        // ---- record sub-loop: wave g gathers its 8 preds' round-r records --
#pragma unroll
        for (int pp = 0; pp < 8; ++pp) {
            const int p = g * 8 + pp;
            const int n = __builtin_amdgcn_readfirstlane((int)cnth[r][p]);
            int j = g * GCAP + __builtin_amdgcn_readfirstlane((int)poff[r][p]);
            float2 a0 = make_float2(0.0f, 0.0f);
            for (int e = 0; e < n; ++e, ++j) {
                const u32 rec = srec32[j];                       // broadcast
                const int sr  = __builtin_amdgcn_readfirstlane((int)rec);
                const int aE  = sr & 0x7F00;                     // SALU: E2 base
                const int aW  = (int)((u32)sr >> 16);            // SALU: WR base
                const u32 sm  = (u32)(sr & 0x100) << 23;         // sign mask
                const u32 ev  = *(const u32*)((const char*)S + aE + laneB);
                const float2 wv2 = *(const float2*)((const char*)WRF + aW + laneB8);
                const float wx = __uint_as_float(__float_as_uint(wv2.x) ^ sm);
                const float wy = __uint_as_float(__float_as_uint(wv2.y) ^ sm);
                a0.x = fmaf(__uint_as_float(ev << 16),          wx, a0.x);
                a0.y = fmaf(__uint_as_float(ev & 0xFFFF0000u),  wy, a0.y);
            }
            acc[pp].x += a0.x;
            acc[pp].y += a0.y;
        }
        __syncthreads();   // WR overwritten next round
    }

    // ======== phase 3: direct stores (R9 epilogue) ========
    if (bf16m) {
        u16* op0 = (u16*)out_v + (size_t)(rowBase + q2) * P_PRED + g * 8;
        u16* op1 = op0 + P_PRED;
        uint4 o0, o1v;
        o0.x  = pack_bf16x2(acc[0].x, acc[1].x);
        o0.y  = pack_bf16x2(acc[2].x, acc[3].x);
        o0.z  = pack_bf16x2(acc[4].x, acc[5].x);
        o0.w  = pack_bf16x2(acc[6].x, acc[7].x);
        o1v.x = pack_bf16x2(acc[0].y, acc[1].y);
        o1v.y = pack_bf16x2(acc[2].y, acc[3].y);
        o1v.z = pack_bf16x2(acc[4].y, acc[5].y);
        o1v.w = pack_bf16x2(acc[6].y, acc[7].y);
        *(uint4*)op0 = o0;
        *(uint4*)op1 = o1v;
    } else {
        float* op0 = (float*)out_v + (size_t)(rowBase + q2) * P_PRED + g * 8;
        float* op1 = op0 + P_PRED;
        *(float4*)(op0)     = make_float4(acc[0].x, acc[1].x, acc[2].x, acc[3].x);
        *(float4*)(op0 + 4) = make_float4(acc[4].x, acc[5].x, acc[6].x, acc[7].x);
        *(float4*)(op1)     = make_float4(acc[0].y, acc[1].y, acc[2].y, acc[3].y);
        *(float4*)(op1 + 4) = make_float4(acc[4].y, acc[5].y, acc[6].y, acc[7].y);
    }
}

extern "C" void kernel_launch(void* const* d_in, const int* in_sizes, int n_in,
                              void* d_out, int out_size, void* d_ws, size_t ws_size,
                              hipStream_t stream_h) {
    const u32* clause_weights = (const u32*)d_in[1]; // bf16 or f32 [128]
    const u32* literal_idx    = (const u32*)d_in[2]; // int32 or int64 [128,3]
    const u32* sign_bits      = (const u32*)d_in[3]; // int32 or int64 [128,3]
    (void)d_ws; (void)ws_size;                       // workspace unused

    ke_wr<<<B_ROWS / RPB, TPB, 0, stream_h>>>(literal_idx, sign_bits,
                                              clause_weights, d_in[0],
                                              d_out);
}

// Round 4
// 124.208 us; speedup vs baseline: 3.1502x; 1.0015x over previous
//
#include <hip/hip_runtime.h>
#include <stdint.h>

typedef unsigned int  u32;
typedef unsigned short u16;

#define B_ROWS 131072
#define P_PRED 64
#define C_CLS  128
#define NPAIR  384               // C*L raw words for dtype detection
#define RPB    128               // rows per block (2 rows per thread-lane)
#define TPB    512               // 8 waves; wave g owns predicates [8g, 8g+8)
#define GCAP   104               // record capacity per 8-pred group (R9-proven)
#define CAPH   24                // per (pred, clause-quarter) scratch cap (mean 1.5)
#define NRND   4                 // clause quarters (rounds)
#define CPR    32                // clauses per round
#define LOG2E  1.4426950408889634f

#if __has_builtin(__builtin_amdgcn_exp2f)
#define EXP2F(x) __builtin_amdgcn_exp2f(x)
#else
#define EXP2F(x) exp2f(x)
#endif

#if __has_builtin(__builtin_amdgcn_rcpf)
#define RCPF(x) __builtin_amdgcn_rcpf(x)
#else
#define RCPF(x) (1.0f / (x))
#endif

__device__ __forceinline__ float bf16_to_f(u16 u) {
    return __uint_as_float(((u32)u) << 16);
}
__device__ __forceinline__ u16 f_to_bf16(float f) {
    u32 u = __float_as_uint(f);
    u += 0x7FFFu + ((u >> 16) & 1u);   // RNE
    return (u16)(u >> 16);
}
__device__ __forceinline__ u32 pack_bf16x2(float lo, float hi) {
    return (u32)f_to_bf16(lo) | ((u32)f_to_bf16(hi) << 16);
}

// ---------------------------------------------------------------------------
// R14: R13 (WR precompute, 4 rounds) with the per-record scalarization
// REMOVED — R13's 2x regression was the ds_read -> lgkmcnt(0) ->
// readfirstlane -> SALU -> ds_read serial chain per record (VALUBusy 28%,
// latency-bound). All record/WR decode is now pure VALU on VGPR-resident
// values, so iterations are independent and the compiler can pipeline
// within and across the 8 unrolled pred-streams (the property that gave
// R9 its 71% VALUBusy).
//   - WR pre-pass (per round of 32 clauses): wrd[c][row] = clamp(w)/D f32
//     in 16 KB LDS; one denom + rcp per clause (was 3x per record in R9).
//   - Record loop: 1 b32 broadcast (srec) + 1 b32 (E2) + 1 b64 (WR) +
//     ~11 VALU + 0 rcp per record (R9: ~20 VALU + 2 rcp).
// LDS = 32K(E2) + 16K(WR) + 3.3K(srec) + 1.5K(meta) = 52.8 KB -> 3
// blocks/CU x 8 waves = 24 waves/CU.
// Workspace d_ws: UNUSED.
// ---------------------------------------------------------------------------
__global__ __launch_bounds__(TPB, 6)
void ke_wr2(const u32* __restrict__ lidx_w,
            const u32* __restrict__ sb_w,
            const u32* __restrict__ w_w,
            const void* __restrict__ atoms_v,
            void* __restrict__ out_v) {
    __shared__ u32 S[8192];                       // 32 KB: prep scratch, then E2
    __shared__ float WRF[CPR * RPB];              // 16 KB: w/D f32 [c&31][row]
    __shared__ u32 srec32[8 * GCAP];              // 3328 B record streams
    __shared__ unsigned char cnth[NRND][P_PRED];  // 256 B stored counts
    __shared__ unsigned char poff[NRND][P_PRED];  // 256 B stream offsets
    __shared__ u32 cslot[C_CLS];                  // 512 B clause slot triples
    __shared__ float cwv[C_CLS];                  // 512 B clamped weights

    const int tid  = threadIdx.x;
    const int lane = tid & 63;
    const int g    = __builtin_amdgcn_readfirstlane(tid >> 6);  // wave 0..7
    const int rowBase = blockIdx.x * RPB;

    // prep scratch aliased into S (dead before E2 staging)
    int* scnt4 = (int*)&S[0];       // [256]  (pred*4 + quarter)
    int* det   = (int*)&S[256];     // [3]
    int* sidx  = (int*)&S[260];     // [384]
    int* ssb   = (int*)&S[644];     // [384]
    u32* recQ  = &S[1032];          // [64*4*CAPH = 6144]

    // ======== phase 0a: init + dtype detect ========
    if (tid < 256) scnt4[tid] = 0;
    if (tid < 3) det[tid] = 1;
    __syncthreads();
    if (tid < NPAIR / 2) {
        if (lidx_w[2 * tid + 1] != 0u) det[0] = 0;   // benign race (all write 0)
        if (sb_w[2 * tid + 1]   != 0u) det[1] = 0;
    }
    if (tid == 0 && (w_w[0] & 0xFFFFu) == 0u) det[2] = 0;
    __syncthreads();
    if (tid < NPAIR) {
        sidx[tid] = (int)(det[0] ? lidx_w[2 * tid] : lidx_w[tid]);
        ssb[tid]  = (int)(det[1] ? sb_w[2 * tid]   : sb_w[tid]);
    }
    __syncthreads();
    const bool bf16m = (det[2] != 0);     // latch before S is reused

    // ======== phase 0b: record insert (by quarter) + clause meta ========
    if (tid < NPAIR) {
        const int c = tid / 3;
        const int p = sidx[tid];
        const int h = c >> 5;                          // clause quarter 0..3
        const int slot = atomicAdd(&scnt4[p * 4 + h], 1);   // int LDS atomic: fine
        const u32 ss = 2u * (u32)p + (ssb[tid] ? 0u : 1u);  // E2 slot (bit0 = neg)
        if (slot < CAPH)
            recQ[(p * 4 + h) * CAPH + slot] =
                (ss << 8) | ((u32)((c & 31) << 9) << 16);   // lo: E2 byte-off; hi: WR byte-off
    }
    if (tid < C_CLS) {
        const int c = tid;
        const u32 s0 = 2u * (u32)sidx[3 * c]     + (ssb[3 * c]     ? 0u : 1u);
        const u32 s1 = 2u * (u32)sidx[3 * c + 1] + (ssb[3 * c + 1] ? 0u : 1u);
        const u32 s2 = 2u * (u32)sidx[3 * c + 2] + (ssb[3 * c + 2] ? 0u : 1u);
        cslot[c] = s0 | (s1 << 8) | (s2 << 16);
        float wraw = bf16m ? bf16_to_f((u16)(w_w[c >> 1] >> ((c & 1) * 16)))
                           : __uint_as_float(w_w[c]);
        cwv[c] = fminf(fmaxf(wraw, 0.0f), 500.0f);
    }
    __syncthreads();

    // ======== phase 0c: CSR copy, quarter-partitioned (thread-per-pred) ====
    if (tid < P_PRED) {
        const int p = tid, gg = p >> 3, gb = gg * 8;
        int off = 0;                           // cursor within group stream
        for (int r = 0; r < NRND; ++r) {
            int offp = off;
            for (int pb = gb; pb < p; ++pb) offp += min(scnt4[pb * 4 + r], CAPH);
            const int n = min(scnt4[p * 4 + r], CAPH);
            int k = 0;
            for (int j2 = 0; j2 < n; ++j2) {
                const int pos = offp + j2;
                if (pos < GCAP) { srec32[gg * GCAP + pos] = recQ[(p * 4 + r) * CAPH + j2]; ++k; }
            }
            poff[r][p] = (unsigned char)min(offp, 255);
            cnth[r][p] = (unsigned char)k;
            for (int pb = gb; pb < gb + 8; ++pb) off += min(scnt4[pb * 4 + r], CAPH);
        }
    }
    __syncthreads();   // streams ready; prep scratch in S now dead

    // ======== phase 1: stage E2 (paired-row b32 writes; R9-verbatim) ========
    {
        const int a  = lane;                     // row pair (2a, 2a+1)
        const int c0 = g * 8;                    // 8-atom chunk per wave
        if (bf16m) {
            const u16* gp0 = (const u16*)atoms_v + (size_t)(rowBase + 2 * a) * P_PRED + c0;
            uint4 v0 = *(const uint4*)gp0;            // row 2a
            uint4 v1 = *(const uint4*)(gp0 + P_PRED); // row 2a+1
            u32 w0[4] = {v0.x, v0.y, v0.z, v0.w};
            u32 w1[4] = {v1.x, v1.y, v1.z, v1.w};
#pragma unroll
            for (int k = 0; k < 4; ++k) {
                float xl0 = __uint_as_float(w0[k] << 16) * LOG2E;
                float xh0 = __uint_as_float(w0[k] & 0xFFFF0000u) * LOG2E;
                float xl1 = __uint_as_float(w1[k] << 16) * LOG2E;
                float xh1 = __uint_as_float(w1[k] & 0xFFFF0000u) * LOG2E;
                float el0 = EXP2F(xl0), eh0 = EXP2F(xh0);
                float el1 = EXP2F(xl1), eh1 = EXP2F(xh1);
                const int m = c0 + 2 * k;
                S[(2 * m)     * 64 + a] = pack_bf16x2(el0, el1);
                S[(2 * m + 1) * 64 + a] = pack_bf16x2(RCPF(el0), RCPF(el1));
                S[(2 * m + 2) * 64 + a] = pack_bf16x2(eh0, eh1);
                S[(2 * m + 3) * 64 + a] = pack_bf16x2(RCPF(eh0), RCPF(eh1));
            }
        } else {
            const float* gp0 = (const float*)atoms_v + (size_t)(rowBase + 2 * a) * P_PRED + c0;
            float4 u0 = *(const float4*)gp0;
            float4 u1 = *(const float4*)(gp0 + 4);
            float4 d0 = *(const float4*)(gp0 + P_PRED);
            float4 d1 = *(const float4*)(gp0 + P_PRED + 4);
            float r0[8] = {u0.x, u0.y, u0.z, u0.w, u1.x, u1.y, u1.z, u1.w};
            float r1[8] = {d0.x, d0.y, d0.z, d0.w, d1.x, d1.y, d1.z, d1.w};
#pragma unroll
            for (int k = 0; k < 8; ++k) {
                float e0 = EXP2F(r0[k] * LOG2E);
                float e1 = EXP2F(r1[k] * LOG2E);
                const int m = c0 + k;
                S[(2 * m)     * 64 + a] = pack_bf16x2(e0, e1);
                S[(2 * m + 1) * 64 + a] = pack_bf16x2(RCPF(e0), RCPF(e1));
            }
        }
    }
    __syncthreads();

    // ======== phase 2: 4 rounds of { WR pre-pass ; record sub-loop } ======
    const int laneB  = lane * 4;     // byte off into an E2 slot row (bf16x2)
    const int laneB8 = lane * 8;     // byte off into a WR clause row (f32x2)
    const int q2 = 2 * lane;         // first row of this lane's pair
    const char* E2b = (const char*)S + laneB;      // per-lane E2 base
    const char* WRb = (const char*)WRF + laneB8;   // per-lane WR base
    float2 acc[8];
#pragma unroll
    for (int pp = 0; pp < 8; ++pp) acc[pp] = make_float2(0.0f, 0.0f);

    for (int r = 0; r < NRND; ++r) {
        // ---- WR pass: wave g computes clauses r*32 + g*4 + k (pure VALU) --
#pragma unroll
        for (int k = 0; k < 4; ++k) {
            const int c  = r * CPR + g * 4 + k;
            const u32 sl = cslot[c];               // uniform-addr LDS read -> VGPR
            const float wS = cwv[c];
            const u32 e0 = *(const u32*)(E2b + ((sl         & 255u) << 8));
            const u32 e1 = *(const u32*)(E2b + (((sl >>  8) & 255u) << 8));
            const u32 e2 = *(const u32*)(E2b + (((sl >> 16) & 255u) << 8));
            const float dx = __uint_as_float(e0 << 16) + __uint_as_float(e1 << 16)
                           + __uint_as_float(e2 << 16);
            const float dy = __uint_as_float(e0 & 0xFFFF0000u)
                           + __uint_as_float(e1 & 0xFFFF0000u)
                           + __uint_as_float(e2 & 0xFFFF0000u);
            float2 wv2;
            wv2.x = wS * RCPF(dx);
            wv2.y = wS * RCPF(dy);
            *(float2*)((char*)WRF + ((c & 31) << 9) + laneB8) = wv2;
        }
        __syncthreads();

        // ---- record sub-loop: pure-VALU decode, pipelineable iterations ---
#pragma unroll
        for (int pp = 0; pp < 8; ++pp) {
            const int p = g * 8 + pp;
            const int n = (int)cnth[r][p];         // wave-uniform LDS read
            int j = g * GCAP + (int)poff[r][p];
            float2 a0 = make_float2(0.0f, 0.0f);
            for (int e = 0; e < n; ++e, ++j) {
                const u32 rec = srec32[j];                           // broadcast
                const u32 ev  = *(const u32*)(E2b + (rec & 0x7F00u));
                const float2 wv2 = *(const float2*)(WRb + (rec >> 16));
                const u32 sm  = (rec & 0x100u) << 23;                // sign->bit31
                const float wx = __uint_as_float(__float_as_uint(wv2.x) ^ sm);
                const float wy = __uint_as_float(__float_as_uint(wv2.y) ^ sm);
                a0.x = fmaf(__uint_as_float(ev << 16),         wx, a0.x);
                a0.y = fmaf(__uint_as_float(ev & 0xFFFF0000u), wy, a0.y);
            }
            acc[pp].x += a0.x;
            acc[pp].y += a0.y;
        }
        __syncthreads();   // WR overwritten next round
    }

    // ======== phase 3: direct stores (R9 epilogue) ========
    if (bf16m) {
        u16* op0 = (u16*)out_v + (size_t)(rowBase + q2) * P_PRED + g * 8;
        u16* op1 = op0 + P_PRED;
        uint4 o0, o1v;
        o0.x  = pack_bf16x2(acc[0].x, acc[1].x);
        o0.y  = pack_bf16x2(acc[2].x, acc[3].x);
        o0.z  = pack_bf16x2(acc[4].x, acc[5].x);
        o0.w  = pack_bf16x2(acc[6].x, acc[7].x);
        o1v.x = pack_bf16x2(acc[0].y, acc[1].y);
        o1v.y = pack_bf16x2(acc[2].y, acc[3].y);
        o1v.z = pack_bf16x2(acc[4].y, acc[5].y);
        o1v.w = pack_bf16x2(acc[6].y, acc[7].y);
        *(uint4*)op0 = o0;
        *(uint4*)op1 = o1v;
    } else {
        float* op0 = (float*)out_v + (size_t)(rowBase + q2) * P_PRED + g * 8;
        float* op1 = op0 + P_PRED;
        *(float4*)(op0)     = make_float4(acc[0].x, acc[1].x, acc[2].x, acc[3].x);
        *(float4*)(op0 + 4) = make_float4(acc[4].x, acc[5].x, acc[6].x, acc[7].x);
        *(float4*)(op1)     = make_float4(acc[0].y, acc[1].y, acc[2].y, acc[3].y);
        *(float4*)(op1 + 4) = make_float4(acc[4].y, acc[5].y, acc[6].y, acc[7].y);
    }
}

extern "C" void kernel_launch(void* const* d_in, const int* in_sizes, int n_in,
                              void* d_out, int out_size, void* d_ws, size_t ws_size,
                              hipStream_t stream_h) {
    const u32* clause_weights = (const u32*)d_in[1]; // bf16 or f32 [128]
    const u32* literal_idx    = (const u32*)d_in[2]; // int32 or int64 [128,3]
    const u32* sign_bits      = (const u32*)d_in[3]; // int32 or int64 [128,3]
    (void)d_ws; (void)ws_size;                       // workspace unused

    ke_wr2<<<B_ROWS / RPB, TPB, 0, stream_h>>>(literal_idx, sign_bits,
                                               clause_weights, d_in[0],
                                               d_out);
}

// Round 5
// 113.703 us; speedup vs baseline: 3.4412x; 1.0924x over previous
//
#include <hip/hip_runtime.h>
#include <stdint.h>

typedef unsigned int  u32;
typedef unsigned short u16;

#define B_ROWS 131072
#define P_PRED 64
#define C_CLS  128
#define NPAIR  384               // C*L raw words for dtype detection
#define RPB    128               // rows per block (2 rows per thread-lane)
#define TPB    1024              // 16 waves; wave g owns preds [4g, 4g+4)
#define CAP    32                // max records per predicate (mean 6, R9-proven)
#define GCAP4  128               // stream capacity per 4-pred group (= 4*CAP, no truncation)
#define LOG2E  1.4426950408889634f

#if __has_builtin(__builtin_amdgcn_exp2f)
#define EXP2F(x) __builtin_amdgcn_exp2f(x)
#else
#define EXP2F(x) exp2f(x)
#endif

#if __has_builtin(__builtin_amdgcn_rcpf)
#define RCPF(x) __builtin_amdgcn_rcpf(x)
#else
#define RCPF(x) (1.0f / (x))
#endif

__device__ __forceinline__ float bf16_to_f(u16 u) {
    return __uint_as_float(((u32)u) << 16);
}
__device__ __forceinline__ u16 f_to_bf16(float f) {
    u32 u = __float_as_uint(f);
    u += 0x7FFFu + ((u >> 16) & 1u);   // RNE
    return (u16)(u >> 16);
}
__device__ __forceinline__ u32 pack_bf16x2(float lo, float hi) {
    return (u32)f_to_bf16(lo) | ((u32)f_to_bf16(hi) << 16);
}

// ---------------------------------------------------------------------------
// R15: SINGLE-PASS WR. R13/R14's regression was the 4-round structure (8
// barriers + 32 runtime-count loops of n~1.5 records: loop overhead ate the
// WR savings; VALUBusy 30%, latency-bound). This keeps R9's proven shape —
// ONE long record pass, streams of n~6, unroll x4 + dual accumulators — and
// adds the full f32 w/D table for ALL 128 clauses in one 64 KB LDS array:
//   - WR pass: 16 waves x 8 clauses, one denom + rcp per clause (vs 3x per
//     record in R9), pure VALU decode, one barrier total.
//   - Record loop: 1 b32 stream read + 1 b32 E2 + 1 b64 WR + ~11 VALU +
//     0 rcp per record (R9: ~15 VALU + 2 rcp + selects).
//   - Group = 4 preds/wave, GCAP4 = 4*CAP -> no truncation beyond R9's CAP.
// LDS = 32K(E2) + 64K(WRF) + 8K(srec) + 1.2K = 105.1 KB -> 1 block/CU x 16
// waves = 4 waves/SIMD (gfx950 allows >64KB static LDS).
// Workspace d_ws: UNUSED.
// ---------------------------------------------------------------------------
__global__ __launch_bounds__(TPB, 4)
void ke_sp(const u32* __restrict__ lidx_w,
           const u32* __restrict__ sb_w,
           const u32* __restrict__ w_w,
           const void* __restrict__ atoms_v,
           void* __restrict__ out_v) {
    __shared__ u32 S[8192];                    // 32 KB: prep scratch, then E2
    __shared__ float WRF[C_CLS * RPB];         // 64 KB: w/D f32 [c][row]
    __shared__ u32 srec32[16 * GCAP4];         // 8 KB record streams (16 groups)
    __shared__ u32 cslot[C_CLS];               // 512 B clause slot triples
    __shared__ float cwv[C_CLS];               // 512 B clamped weights
    __shared__ unsigned char cnt8[P_PRED];     // 64 B per-pred counts

    const int tid  = threadIdx.x;
    const int lane = tid & 63;
    const int g    = __builtin_amdgcn_readfirstlane(tid >> 6);  // wave 0..15
    const int rowBase = blockIdx.x * RPB;

    // prep scratch aliased into S (dead before E2 staging)
    int* scnt = (int*)&S[0];        // [64]
    int* det  = (int*)&S[64];       // [3]
    int* sidx = (int*)&S[128];      // [384]
    int* ssb  = (int*)&S[512];      // [384]
    u32* recQ = &S[1024];           // [64*CAP = 2048]

    // ======== phase 0a: init + dtype detect ========
    if (tid < P_PRED) scnt[tid] = 0;
    if (tid < 3) det[tid] = 1;
    __syncthreads();
    if (tid < NPAIR / 2) {
        if (lidx_w[2 * tid + 1] != 0u) det[0] = 0;   // benign race (all write 0)
        if (sb_w[2 * tid + 1]   != 0u) det[1] = 0;
    }
    if (tid == 0 && (w_w[0] & 0xFFFFu) == 0u) det[2] = 0;
    __syncthreads();
    if (tid < NPAIR) {
        sidx[tid] = (int)(det[0] ? lidx_w[2 * tid] : lidx_w[tid]);
        ssb[tid]  = (int)(det[1] ? sb_w[2 * tid]   : sb_w[tid]);
    }
    __syncthreads();
    const bool bf16m = (det[2] != 0);     // latch before S is reused

    // ======== phase 0b: record insert + clause meta ========
    if (tid < NPAIR) {
        const int c = tid / 3;
        const int p = sidx[tid];
        const int slot = atomicAdd(&scnt[p], 1);            // int LDS atomic: fine
        const u32 ss = 2u * (u32)p + (ssb[tid] ? 0u : 1u);  // E2 slot (bit0 = neg)
        if (slot < CAP)
            recQ[p * CAP + slot] =
                (ss << 8) | ((u32)(c << 9) << 16);  // lo: E2 byte-off (+sign bit8); hi: WR byte-off
    }
    if (tid < C_CLS) {
        const int c = tid;
        const u32 s0 = 2u * (u32)sidx[3 * c]     + (ssb[3 * c]     ? 0u : 1u);
        const u32 s1 = 2u * (u32)sidx[3 * c + 1] + (ssb[3 * c + 1] ? 0u : 1u);
        const u32 s2 = 2u * (u32)sidx[3 * c + 2] + (ssb[3 * c + 2] ? 0u : 1u);
        cslot[c] = s0 | (s1 << 8) | (s2 << 16);
        float wraw = bf16m ? bf16_to_f((u16)(w_w[c >> 1] >> ((c & 1) * 16)))
                           : __uint_as_float(w_w[c]);
        cwv[c] = fminf(fmaxf(wraw, 0.0f), 500.0f);
    }
    __syncthreads();

    // ======== phase 0c: CSR copy into 4-pred group streams ========
    if (tid < P_PRED) {
        const int p = tid, gg = p >> 2, gb = gg * 4;
        int offp = 0;
        for (int pb = gb; pb < p; ++pb) offp += min(scnt[pb], CAP);
        const int n = min(scnt[p], CAP);
        for (int j2 = 0; j2 < n; ++j2)
            srec32[gg * GCAP4 + offp + j2] = recQ[p * CAP + j2];   // offp+n <= 128 always
        cnt8[p] = (unsigned char)n;
    }
    __syncthreads();   // streams ready; prep scratch in S now dead

    // ======== phase 1: stage E2 (paired-row b32 writes) ========
    {
        const int a  = lane;                     // row pair (2a, 2a+1)
        const int c0 = g * 4;                    // 4-atom chunk (16 waves x 4)
        if (bf16m) {
            const u16* gp0 = (const u16*)atoms_v + (size_t)(rowBase + 2 * a) * P_PRED + c0;
            uint2 v0 = *(const uint2*)gp0;            // row 2a, atoms c0..c0+3
            uint2 v1 = *(const uint2*)(gp0 + P_PRED); // row 2a+1
            u32 w0[2] = {v0.x, v0.y};
            u32 w1[2] = {v1.x, v1.y};
#pragma unroll
            for (int k = 0; k < 2; ++k) {
                float xl0 = __uint_as_float(w0[k] << 16) * LOG2E;
                float xh0 = __uint_as_float(w0[k] & 0xFFFF0000u) * LOG2E;
                float xl1 = __uint_as_float(w1[k] << 16) * LOG2E;
                float xh1 = __uint_as_float(w1[k] & 0xFFFF0000u) * LOG2E;
                float el0 = EXP2F(xl0), eh0 = EXP2F(xh0);
                float el1 = EXP2F(xl1), eh1 = EXP2F(xh1);
                const int m = c0 + 2 * k;
                S[(2 * m)     * 64 + a] = pack_bf16x2(el0, el1);
                S[(2 * m + 1) * 64 + a] = pack_bf16x2(RCPF(el0), RCPF(el1));
                S[(2 * m + 2) * 64 + a] = pack_bf16x2(eh0, eh1);
                S[(2 * m + 3) * 64 + a] = pack_bf16x2(RCPF(eh0), RCPF(eh1));
            }
        } else {
            const float* gp0 = (const float*)atoms_v + (size_t)(rowBase + 2 * a) * P_PRED + c0;
            float4 u0 = *(const float4*)gp0;             // row 2a, atoms c0..c0+3
            float4 d0 = *(const float4*)(gp0 + P_PRED);  // row 2a+1
            float r0[4] = {u0.x, u0.y, u0.z, u0.w};
            float r1[4] = {d0.x, d0.y, d0.z, d0.w};
#pragma unroll
            for (int k = 0; k < 4; ++k) {
                float e0 = EXP2F(r0[k] * LOG2E);
                float e1 = EXP2F(r1[k] * LOG2E);
                const int m = c0 + k;
                S[(2 * m)     * 64 + a] = pack_bf16x2(e0, e1);
                S[(2 * m + 1) * 64 + a] = pack_bf16x2(RCPF(e0), RCPF(e1));
            }
        }
    }
    __syncthreads();

    // ======== phase 2a: WR pass — all 128 clauses, one barrier ========
    const int laneB  = lane * 4;     // byte off into an E2 slot row (bf16x2)
    const int laneB8 = lane * 8;     // byte off into a WR clause row (f32x2)
    const char* E2b = (const char*)S + laneB;
    const char* WRb = (const char*)WRF + laneB8;
    {
#pragma unroll
        for (int k = 0; k < 8; ++k) {
            const int c  = g * 8 + k;              // wave-uniform clause
            const u32 sl = cslot[c];               // broadcast LDS read
            const float wS = cwv[c];
            const u32 e0 = *(const u32*)(E2b + ((sl         & 255u) << 8));
            const u32 e1 = *(const u32*)(E2b + (((sl >>  8) & 255u) << 8));
            const u32 e2 = *(const u32*)(E2b + (((sl >> 16) & 255u) << 8));
            const float dx = __uint_as_float(e0 << 16) + __uint_as_float(e1 << 16)
                           + __uint_as_float(e2 << 16);
            const float dy = __uint_as_float(e0 & 0xFFFF0000u)
                           + __uint_as_float(e1 & 0xFFFF0000u)
                           + __uint_as_float(e2 & 0xFFFF0000u);
            float2 wv2;
            wv2.x = wS * RCPF(dx);
            wv2.y = wS * RCPF(dy);
            *(float2*)((char*)WRF + (c << 9) + laneB8) = wv2;
        }
    }
    __syncthreads();

    // ======== phase 2b: record loop — single pass, long streams ========
    const int q2 = 2 * lane;               // first row of this lane's pair
    float2 acc[4];
    const u32 cw4 = *(const u32*)&cnt8[g * 4];     // 4 counts in one read
    int j = g * GCAP4;                             // stream cursor

#pragma unroll
    for (int pp = 0; pp < 4; ++pp) {
        const int n = (int)((cw4 >> (8 * pp)) & 255u);
        float2 a0 = make_float2(0.0f, 0.0f);
        float2 a1 = make_float2(0.0f, 0.0f);

#define REC_BODY(J, A)                                                        \
        {                                                                     \
            const u32 rec = srec32[J];                       /* broadcast */  \
            const u32 ev  = *(const u32*)(E2b + (rec & 0x7F00u));             \
            const float2 wv2 = *(const float2*)(WRb + (rec >> 16));           \
            const u32 sm  = (rec & 0x100u) << 23;            /* sign->b31 */  \
            const float wx = __uint_as_float(__float_as_uint(wv2.x) ^ sm);    \
            const float wy = __uint_as_float(__float_as_uint(wv2.y) ^ sm);    \
            A.x = fmaf(__uint_as_float(ev << 16),         wx, A.x);           \
            A.y = fmaf(__uint_as_float(ev & 0xFFFF0000u), wy, A.y);           \
        }

        int e = 0;
        for (; e + 3 < n; e += 4) {        // unroll x4, dual accumulators
            REC_BODY(j,     a0)
            REC_BODY(j + 1, a1)
            REC_BODY(j + 2, a0)
            REC_BODY(j + 3, a1)
            j += 4;
        }
        for (; e < n; ++e, ++j) REC_BODY(j, a0)
#undef REC_BODY
        acc[pp] = make_float2(a0.x + a1.x, a0.y + a1.y);
    }

    // ======== phase 3: direct stores ========
    if (bf16m) {
        u16* op0 = (u16*)out_v + (size_t)(rowBase + q2) * P_PRED + g * 4;
        uint2 o0, o1;
        o0.x = pack_bf16x2(acc[0].x, acc[1].x);
        o0.y = pack_bf16x2(acc[2].x, acc[3].x);
        o1.x = pack_bf16x2(acc[0].y, acc[1].y);
        o1.y = pack_bf16x2(acc[2].y, acc[3].y);
        *(uint2*)op0            = o0;
        *(uint2*)(op0 + P_PRED) = o1;
    } else {
        float* op0 = (float*)out_v + (size_t)(rowBase + q2) * P_PRED + g * 4;
        *(float4*)op0            = make_float4(acc[0].x, acc[1].x, acc[2].x, acc[3].x);
        *(float4*)(op0 + P_PRED) = make_float4(acc[0].y, acc[1].y, acc[2].y, acc[3].y);
    }
}

extern "C" void kernel_launch(void* const* d_in, const int* in_sizes, int n_in,
                              void* d_out, int out_size, void* d_ws, size_t ws_size,
                              hipStream_t stream_h) {
    const u32* clause_weights = (const u32*)d_in[1]; // bf16 or f32 [128]
    const u32* literal_idx    = (const u32*)d_in[2]; // int32 or int64 [128,3]
    const u32* sign_bits      = (const u32*)d_in[3]; // int32 or int64 [128,3]
    (void)d_ws; (void)ws_size;                       // workspace unused

    ke_sp<<<B_ROWS / RPB, TPB, 0, stream_h>>>(literal_idx, sign_bits,
                                              clause_weights, d_in[0],
                                              d_out);
}

// Round 6
// 108.852 us; speedup vs baseline: 3.5945x; 1.0446x over previous
//
#include <hip/hip_runtime.h>
#include <stdint.h>

typedef unsigned int  u32;
typedef unsigned short u16;

#define B_ROWS 131072
#define P_PRED 64
#define C_CLS  128
#define NPAIR  384               // C*L raw words for dtype detection
#define RPB    128               // rows per block (2 rows per thread-lane)
#define TPB    1024              // 16 waves; wave g owns preds [4g, 4g+4)
#define NH     2                 // clause halves (rounds)
#define CPH    64                // clauses per half
#define CAPH   24                // per (pred, half) scratch cap (mean 3)
#define GCAP4  128               // stream capacity per 4-pred group (both halves)
#define LOG2E  1.4426950408889634f

#if __has_builtin(__builtin_amdgcn_exp2f)
#define EXP2F(x) __builtin_amdgcn_exp2f(x)
#else
#define EXP2F(x) exp2f(x)
#endif

#if __has_builtin(__builtin_amdgcn_rcpf)
#define RCPF(x) __builtin_amdgcn_rcpf(x)
#else
#define RCPF(x) (1.0f / (x))
#endif

__device__ __forceinline__ float bf16_to_f(u16 u) {
    return __uint_as_float(((u32)u) << 16);
}
__device__ __forceinline__ u16 f_to_bf16(float f) {
    u32 u = __float_as_uint(f);
    u += 0x7FFFu + ((u >> 16) & 1u);   // RNE
    return (u16)(u >> 16);
}
__device__ __forceinline__ u32 pack_bf16x2(float lo, float hi) {
    return (u32)f_to_bf16(lo) | ((u32)f_to_bf16(hi) << 16);
}

// ---------------------------------------------------------------------------
// R16: 2-ROUND WR at 8 waves/SIMD. The ladder: R9 (26.5us, 71% busy, 8
// waves/SIMD, no WR) / R15 (44.4us, 30% busy, 4 waves/SIMD, single-pass WR —
// issue cut to 13.3us but LDS 105KB killed occupancy) / R13-14 (56us, 4-round
// WR: streams n~1.5 too short). This round: WRF covers 64 clauses at a time
// (f32, 32 KB), TWO rounds -> LDS 73.3 KB -> 2 blocks/CU x 16 waves = 8
// waves/SIMD (R9's proven hiding regime) with streams n~3/pred/round and
// only +2 barriers vs R15. Record-loop body identical to R15 (pure-VALU
// decode, f32 w/D -> bit-identical arithmetic, no new rounding).
// LDS = 32K(E2) + 32K(WRF) + 8K(srec) + 1.3K = 73.3 KB.
// Workspace d_ws: UNUSED.
// ---------------------------------------------------------------------------
__global__ __launch_bounds__(TPB, 8)
void ke_h2(const u32* __restrict__ lidx_w,
           const u32* __restrict__ sb_w,
           const u32* __restrict__ w_w,
           const void* __restrict__ atoms_v,
           void* __restrict__ out_v) {
    __shared__ u32 S[8192];                    // 32 KB: prep scratch, then E2
    __shared__ float WRF[CPH * RPB];           // 32 KB: w/D f32 [c&63][row]
    __shared__ u32 srec32[16 * GCAP4];         // 8 KB record streams (16 groups)
    __shared__ u32 cslot[C_CLS];               // 512 B clause slot triples
    __shared__ float cwv[C_CLS];               // 512 B clamped weights
    __shared__ u32 cntw[NH][P_PRED / 4];       // 128 B stored counts (bytes)
    __shared__ u32 poffw[NH][P_PRED / 4];      // 128 B stream offsets (bytes)

    const int tid  = threadIdx.x;
    const int lane = tid & 63;
    const int g    = __builtin_amdgcn_readfirstlane(tid >> 6);  // wave 0..15
    const int rowBase = blockIdx.x * RPB;

    // prep scratch aliased into S (dead before E2 staging)
    int* scnt2 = (int*)&S[0];       // [128]  (pred*2 + half)
    int* det   = (int*)&S[128];     // [3]
    int* sidx  = (int*)&S[140];     // [384]
    int* ssb   = (int*)&S[524];     // [384]
    u32* recQ  = &S[1024];          // [64*2*CAPH = 3072]

    // ======== phase 0a: init + dtype detect ========
    if (tid < 128) scnt2[tid] = 0;
    if (tid < 3) det[tid] = 1;
    __syncthreads();
    if (tid < NPAIR / 2) {
        if (lidx_w[2 * tid + 1] != 0u) det[0] = 0;   // benign race (all write 0)
        if (sb_w[2 * tid + 1]   != 0u) det[1] = 0;
    }
    if (tid == 0 && (w_w[0] & 0xFFFFu) == 0u) det[2] = 0;
    __syncthreads();
    if (tid < NPAIR) {
        sidx[tid] = (int)(det[0] ? lidx_w[2 * tid] : lidx_w[tid]);
        ssb[tid]  = (int)(det[1] ? sb_w[2 * tid]   : sb_w[tid]);
    }
    __syncthreads();
    const bool bf16m = (det[2] != 0);     // latch before S is reused

    // ======== phase 0b: record insert (by half) + clause meta ========
    if (tid < NPAIR) {
        const int c = tid / 3;
        const int p = sidx[tid];
        const int h = c >> 6;                               // clause half 0/1
        const int slot = atomicAdd(&scnt2[p * 2 + h], 1);   // int LDS atomic: fine
        const u32 ss = 2u * (u32)p + (ssb[tid] ? 0u : 1u);  // E2 slot (bit0 = neg)
        if (slot < CAPH)
            recQ[(p * 2 + h) * CAPH + slot] =
                (ss << 8) | ((u32)((c & 63) << 9) << 16);   // lo: E2 byte-off (+sign bit8); hi: WR byte-off
    }
    if (tid < C_CLS) {
        const int c = tid;
        const u32 s0 = 2u * (u32)sidx[3 * c]     + (ssb[3 * c]     ? 0u : 1u);
        const u32 s1 = 2u * (u32)sidx[3 * c + 1] + (ssb[3 * c + 1] ? 0u : 1u);
        const u32 s2 = 2u * (u32)sidx[3 * c + 2] + (ssb[3 * c + 2] ? 0u : 1u);
        cslot[c] = s0 | (s1 << 8) | (s2 << 16);
        float wraw = bf16m ? bf16_to_f((u16)(w_w[c >> 1] >> ((c & 1) * 16)))
                           : __uint_as_float(w_w[c]);
        cwv[c] = fminf(fmaxf(wraw, 0.0f), 500.0f);
    }
    __syncthreads();

    // ======== phase 0c: CSR copy into 4-pred group streams (by half) ======
    if (tid < P_PRED) {
        const int p = tid, gg = p >> 2, gb = gg * 4;
        // half-0 region size for this group
        int G0 = 0;
        for (int pb = gb; pb < gb + 4; ++pb) G0 += min(scnt2[pb * 2], CAPH);
        unsigned char* cb0 = (unsigned char*)&cntw[0][0];
        unsigned char* cb1 = (unsigned char*)&cntw[1][0];
        unsigned char* pb0 = (unsigned char*)&poffw[0][0];
        unsigned char* pb1 = (unsigned char*)&poffw[1][0];
        // half 0
        {
            int off = 0;
            for (int pb = gb; pb < p; ++pb) off += min(scnt2[pb * 2], CAPH);
            const int n = min(scnt2[p * 2], CAPH);
            int k = 0;
            for (int j2 = 0; j2 < n; ++j2) {
                const int pos = off + j2;
                if (pos < GCAP4) { srec32[gg * GCAP4 + pos] = recQ[(p * 2) * CAPH + j2]; ++k; }
            }
            pb0[p] = (unsigned char)min(off, 255);
            cb0[p] = (unsigned char)k;
        }
        // half 1 (region starts at G0)
        {
            int off = G0;
            for (int pb = gb; pb < p; ++pb) off += min(scnt2[pb * 2 + 1], CAPH);
            const int n = min(scnt2[p * 2 + 1], CAPH);
            int k = 0;
            for (int j2 = 0; j2 < n; ++j2) {
                const int pos = off + j2;
                if (pos < GCAP4) { srec32[gg * GCAP4 + pos] = recQ[(p * 2 + 1) * CAPH + j2]; ++k; }
            }
            pb1[p] = (unsigned char)min(off, 255);
            cb1[p] = (unsigned char)k;
        }
    }
    __syncthreads();   // streams ready; prep scratch in S now dead

    // ======== phase 1: stage E2 (paired-row b32 writes) ========
    {
        const int a  = lane;                     // row pair (2a, 2a+1)
        const int c0 = g * 4;                    // 4-atom chunk (16 waves x 4)
        if (bf16m) {
            const u16* gp0 = (const u16*)atoms_v + (size_t)(rowBase + 2 * a) * P_PRED + c0;
            uint2 v0 = *(const uint2*)gp0;            // row 2a, atoms c0..c0+3
            uint2 v1 = *(const uint2*)(gp0 + P_PRED); // row 2a+1
            u32 w0[2] = {v0.x, v0.y};
            u32 w1[2] = {v1.x, v1.y};
#pragma unroll
            for (int k = 0; k < 2; ++k) {
                float xl0 = __uint_as_float(w0[k] << 16) * LOG2E;
                float xh0 = __uint_as_float(w0[k] & 0xFFFF0000u) * LOG2E;
                float xl1 = __uint_as_float(w1[k] << 16) * LOG2E;
                float xh1 = __uint_as_float(w1[k] & 0xFFFF0000u) * LOG2E;
                float el0 = EXP2F(xl0), eh0 = EXP2F(xh0);
                float el1 = EXP2F(xl1), eh1 = EXP2F(xh1);
                const int m = c0 + 2 * k;
                S[(2 * m)     * 64 + a] = pack_bf16x2(el0, el1);
                S[(2 * m + 1) * 64 + a] = pack_bf16x2(RCPF(el0), RCPF(el1));
                S[(2 * m + 2) * 64 + a] = pack_bf16x2(eh0, eh1);
                S[(2 * m + 3) * 64 + a] = pack_bf16x2(RCPF(eh0), RCPF(eh1));
            }
        } else {
            const float* gp0 = (const float*)atoms_v + (size_t)(rowBase + 2 * a) * P_PRED + c0;
            float4 u0 = *(const float4*)gp0;             // row 2a, atoms c0..c0+3
            float4 d0 = *(const float4*)(gp0 + P_PRED);  // row 2a+1
            float r0[4] = {u0.x, u0.y, u0.z, u0.w};
            float r1[4] = {d0.x, d0.y, d0.z, d0.w};
#pragma unroll
            for (int k = 0; k < 4; ++k) {
                float e0 = EXP2F(r0[k] * LOG2E);
                float e1 = EXP2F(r1[k] * LOG2E);
                const int m = c0 + k;
                S[(2 * m)     * 64 + a] = pack_bf16x2(e0, e1);
                S[(2 * m + 1) * 64 + a] = pack_bf16x2(RCPF(e0), RCPF(e1));
            }
        }
    }
    __syncthreads();

    // ======== phase 2: 2 rounds of { WR pass ; record sub-loop } ========
    const int laneB  = lane * 4;     // byte off into an E2 slot row (bf16x2)
    const int laneB8 = lane * 8;     // byte off into a WR clause row (f32x2)
    const char* E2b = (const char*)S + laneB;
    const char* WRb = (const char*)WRF + laneB8;
    float2 acc[4];
#pragma unroll
    for (int pp = 0; pp < 4; ++pp) acc[pp] = make_float2(0.0f, 0.0f);

    for (int h = 0; h < NH; ++h) {
        // ---- WR pass: wave g computes clauses h*64 + g*4 + k (pure VALU) --
#pragma unroll
        for (int k = 0; k < 4; ++k) {
            const int c  = h * CPH + g * 4 + k;    // wave-uniform clause
            const u32 sl = cslot[c];               // broadcast LDS read
            const float wS = cwv[c];
            const u32 e0 = *(const u32*)(E2b + ((sl         & 255u) << 8));
            const u32 e1 = *(const u32*)(E2b + (((sl >>  8) & 255u) << 8));
            const u32 e2 = *(const u32*)(E2b + (((sl >> 16) & 255u) << 8));
            const float dx = __uint_as_float(e0 << 16) + __uint_as_float(e1 << 16)
                           + __uint_as_float(e2 << 16);
            const float dy = __uint_as_float(e0 & 0xFFFF0000u)
                           + __uint_as_float(e1 & 0xFFFF0000u)
                           + __uint_as_float(e2 & 0xFFFF0000u);
            float2 wv2;
            wv2.x = wS * RCPF(dx);
            wv2.y = wS * RCPF(dy);
            *(float2*)((char*)WRF + ((c & 63) << 9) + laneB8) = wv2;
        }
        __syncthreads();

        // ---- record sub-loop: R15 body verbatim, streams n~3 ----
        const u32 cw = cntw[h][g];                 // 4 counts in one read
        const u32 pw = poffw[h][g];                // 4 offsets in one read
#pragma unroll
        for (int pp = 0; pp < 4; ++pp) {
            const int n = (int)((cw >> (8 * pp)) & 255u);
            int j = g * GCAP4 + (int)((pw >> (8 * pp)) & 255u);
            float2 a0 = make_float2(0.0f, 0.0f);
            float2 a1 = make_float2(0.0f, 0.0f);

#define REC_BODY(J, A)                                                        \
            {                                                                 \
                const u32 rec = srec32[J];                   /* broadcast */  \
                const u32 ev  = *(const u32*)(E2b + (rec & 0x7F00u));         \
                const float2 wv2 = *(const float2*)(WRb + (rec >> 16));       \
                const u32 sm  = (rec & 0x100u) << 23;        /* sign->b31 */  \
                const float wx = __uint_as_float(__float_as_uint(wv2.x) ^ sm);\
                const float wy = __uint_as_float(__float_as_uint(wv2.y) ^ sm);\
                A.x = fmaf(__uint_as_float(ev << 16),         wx, A.x);       \
                A.y = fmaf(__uint_as_float(ev & 0xFFFF0000u), wy, A.y);       \
            }

            int e = 0;
            for (; e + 3 < n; e += 4) {        // unroll x4, dual accumulators
                REC_BODY(j,     a0)
                REC_BODY(j + 1, a1)
                REC_BODY(j + 2, a0)
                REC_BODY(j + 3, a1)
                j += 4;
            }
            for (; e < n; ++e, ++j) REC_BODY(j, a0)
#undef REC_BODY
            acc[pp].x += a0.x + a1.x;
            acc[pp].y += a0.y + a1.y;
        }
        if (h == 0) __syncthreads();   // WRF overwritten next round
    }

    // ======== phase 3: direct stores ========
    const int q2 = 2 * lane;               // first row of this lane's pair
    if (bf16m) {
        u16* op0 = (u16*)out_v + (size_t)(rowBase + q2) * P_PRED + g * 4;
        uint2 o0, o1;
        o0.x = pack_bf16x2(acc[0].x, acc[1].x);
        o0.y = pack_bf16x2(acc[2].x, acc[3].x);
        o1.x = pack_bf16x2(acc[0].y, acc[1].y);
        o1.y = pack_bf16x2(acc[2].y, acc[3].y);
        *(uint2*)op0            = o0;
        *(uint2*)(op0 + P_PRED) = o1;
    } else {
        float* op0 = (float*)out_v + (size_t)(rowBase + q2) * P_PRED + g * 4;
        *(float4*)op0            = make_float4(acc[0].x, acc[1].x, acc[2].x, acc[3].x);
        *(float4*)(op0 + P_PRED) = make_float4(acc[0].y, acc[1].y, acc[2].y, acc[3].y);
    }
}

extern "C" void kernel_launch(void* const* d_in, const int* in_sizes, int n_in,
                              void* d_out, int out_size, void* d_ws, size_t ws_size,
                              hipStream_t stream_h) {
    const u32* clause_weights = (const u32*)d_in[1]; // bf16 or f32 [128]
    const u32* literal_idx    = (const u32*)d_in[2]; // int32 or int64 [128,3]
    const u32* sign_bits      = (const u32*)d_in[3]; // int32 or int64 [128,3]
    (void)d_ws; (void)ws_size;                       // workspace unused

    ke_h2<<<B_ROWS / RPB, TPB, 0, stream_h>>>(literal_idx, sign_bits,
                                              clause_weights, d_in[0],
                                              d_out);
}

// Round 7
// 101.692 us; speedup vs baseline: 3.8476x; 1.0704x over previous
//
#include <hip/hip_runtime.h>
#include <hip/hip_fp16.h>
#include <stdint.h>

typedef unsigned int  u32;
typedef unsigned short u16;

#define B_ROWS 131072
#define P_PRED 64
#define C_CLS  128
#define NPAIR  384               // C*L raw words for dtype detection
#define CAP    32                // max records per predicate (mean 6)
#define RPB    128               // rows per block (2 rows per thread)
#define TPB    512               // 8 waves; wave g owns predicates [8g, 8g+8)
#define GCAP   104               // record capacity per 8-pred group (mean 48)
#define LOG2E  1.4426950408889634f

#if __has_builtin(__builtin_amdgcn_exp2f)
#define EXP2F(x) __builtin_amdgcn_exp2f(x)
#else
#define EXP2F(x) exp2f(x)
#endif

#if __has_builtin(__builtin_amdgcn_rcpf)
#define RCPF(x) __builtin_amdgcn_rcpf(x)
#else
#define RCPF(x) (1.0f / (x))
#endif

__device__ __forceinline__ float bf16_to_f(u16 u) {
    return __uint_as_float(((u32)u) << 16);
}
__device__ __forceinline__ u16 f_to_bf16(float f) {
    u32 u = __float_as_uint(f);
    u += 0x7FFFu + ((u >> 16) & 1u);   // RNE
    return (u16)(u >> 16);
}
__device__ __forceinline__ u32 pack_bf16x2(float lo, float hi) {
    return (u32)f_to_bf16(lo) | ((u32)f_to_bf16(hi) << 16);
}
// fp16 pair helpers (u32 <-> __half2 bitcasts)
__device__ __forceinline__ u32 h2u(__half2 h) { union { __half2 h; u32 u; } v; v.h = h; return v.u; }
__device__ __forceinline__ __half2 u2h(u32 u) { union { __half2 h; u32 u; } v; v.u = u; return v.h; }
__device__ __forceinline__ u32 pack_f16x2(float lo, float hi) {
    return h2u(__floats2half2_rn(lo, hi));     // RN: 2x v_cvt_f16_f32 + pack
}

// ---------------------------------------------------------------------------
// R17: R0/R9 kernel VERBATIM in structure (single pass, NO post-staging
// barriers, 39 KB LDS -> 4 blocks/CU, long streams — every barrier-adding
// WR rewrite in R12-R16 lost to it), with the record-loop ARITHMETIC moved
// to packed fp16:
//   - E2 stores half2 (row 2a, row 2a+1) instead of bf16x2 — each u32 LDS
//     word is directly operable, no unpack shifts/ands.
//   - denominator: 2x v_pk_add_f16 (was 4 f32 adds + 8 unpack ops)
//   - self-slot select: 1 cndmask on the packed word (was 2)
//   - weight: pre-signed duplicated half2 in srec -> v_pk_mul + v_pk_fma
//   - only rcp stays per-element (h2rcp)
//   ~34-38 VALU-cyc/record vs ~54 (record loop = 99% of body per R11 probe,
//   71% VALUBusy -> issue-bound). fp16 (10-bit mantissa) > bf16 (7-bit)
//   staging precision; fp16 accumulation chains are <=3 adds per dual acc.
// Workspace d_ws: UNUSED.
// ---------------------------------------------------------------------------
__global__ __launch_bounds__(TPB, 8)
void ke_fp16(const u32* __restrict__ lidx_w,
             const u32* __restrict__ sb_w,
             const u32* __restrict__ w_w,
             const void* __restrict__ atoms_v,
             void* __restrict__ out_v) {
    __shared__ u32 S[8192];                   // 32 KB: prep scratch, then E2
    __shared__ uint2 srec[8 * GCAP];          // 6656 B (persists all phases)
    __shared__ unsigned char cnt8[P_PRED];    // 64 B

    const int tid = threadIdx.x;
    const int lane = tid & 63;
    const int g = __builtin_amdgcn_readfirstlane(tid >> 6);  // 0..7, SGPR
    const int rowBase = blockIdx.x * RPB;

    // ======== phase 0: inline prep (scratch aliased into S) ========
    int*   scnt  = (int*)&S[0];       // [64]
    int*   det   = (int*)&S[64];      // [3]
    int*   sidx  = (int*)&S[128];     // [384]
    int*   ssb   = (int*)&S[512];     // [384]
    u32*   recPk = &S[1024];          // [64][32]
    u32*   recWH = &S[3072];          // [64][32] pre-signed half2-dup weight

    if (tid < P_PRED) scnt[tid] = 0;
    if (tid < 3) det[tid] = 1;
    __syncthreads();
    if (tid < NPAIR / 2) {
        if (lidx_w[2 * tid + 1] != 0u) det[0] = 0;   // benign race (all write 0)
        if (sb_w[2 * tid + 1]   != 0u) det[1] = 0;
    }
    if (tid == 0 && (w_w[0] & 0xFFFFu) == 0u) det[2] = 0;
    __syncthreads();
    if (tid < NPAIR) {
        sidx[tid] = (int)(det[0] ? lidx_w[2 * tid] : lidx_w[tid]);
        ssb[tid]  = (int)(det[1] ? sb_w[2 * tid]   : sb_w[tid]);
    }
    __syncthreads();
    const bool bf16m = (det[2] != 0);            // latch before S is reused
    if (tid < NPAIR) {
        const int c = tid / 3;
        const int l = tid - c * 3;
        const int base = c * 3;
        const int o1 = base + (l == 0 ? 1 : 0);
        const int o2 = base + (l == 2 ? 1 : 2);
        const int p = sidx[tid];
        const int slot = atomicAdd(&scnt[p], 1); // prep-only LDS atomics: fine
        float wraw = bf16m ? bf16_to_f((u16)(w_w[c / 2] >> ((c & 1) * 16)))
                           : __uint_as_float(w_w[c]);
        float wc = fminf(fmaxf(wraw, 0.0f), 500.0f);
        if (slot < CAP) {
            u32 s1 = 2u * (u32)sidx[o1] + (ssb[o1] ? 0u : 1u);
            u32 s2 = 2u * (u32)sidx[o2] + (ssb[o2] ? 0u : 1u);
            recPk[p * CAP + slot] = (ssb[tid] ? 0u : 1u) | (s1 << 8) | (s2 << 16);
            u32 wh2 = pack_f16x2(wc, wc);                 // duplicated half2
            if (!ssb[tid]) wh2 ^= 0x80008000u;            // pre-signed
            recWH[p * CAP + slot] = wh2;
        }
    }
    __syncthreads();
    if (tid < P_PRED) {
        const int p = tid;
        const int gg = p >> 3;
        const int n = min(scnt[p], CAP);
        int off = 0;
        for (int pb = gg * 8; pb < p; ++pb) off += min(scnt[pb], CAP);
        int ncl = 0;
        for (int j = 0; j < n; ++j) {
            if (off + j < GCAP) {
                srec[gg * GCAP + off + j] =
                    make_uint2(recPk[p * CAP + j], recWH[p * CAP + j]);
                ++ncl;
            }
        }
        cnt8[p] = (unsigned char)ncl;
    }
    __syncthreads();   // srec/cnt8 ready; prep scratch in S now dead

    // ======== phase 1: stage E2 as half2 (paired-row b32 writes) ========
    {
        const int a = tid & 63;                  // row pair (2a, 2a+1)
        const int c0 = (tid >> 6) * 8;           // 8-atom chunk
        if (bf16m) {
            const u16* gp0 = (const u16*)atoms_v + (size_t)(rowBase + 2 * a) * P_PRED + c0;
            uint4 v0 = *(const uint4*)gp0;            // row 2a
            uint4 v1 = *(const uint4*)(gp0 + P_PRED); // row 2a+1
            u32 w0[4] = {v0.x, v0.y, v0.z, v0.w};
            u32 w1[4] = {v1.x, v1.y, v1.z, v1.w};
#pragma unroll
            for (int k = 0; k < 4; ++k) {
                float xl0 = __uint_as_float(w0[k] << 16) * LOG2E;
                float xh0 = __uint_as_float(w0[k] & 0xFFFF0000u) * LOG2E;
                float xl1 = __uint_as_float(w1[k] << 16) * LOG2E;
                float xh1 = __uint_as_float(w1[k] & 0xFFFF0000u) * LOG2E;
                float el0 = EXP2F(xl0), eh0 = EXP2F(xh0);
                float el1 = EXP2F(xl1), eh1 = EXP2F(xh1);
                const int m = c0 + 2 * k;
                S[(2 * m)     * 64 + a] = pack_f16x2(el0, el1);
                S[(2 * m + 1) * 64 + a] = pack_f16x2(RCPF(el0), RCPF(el1));
                S[(2 * m + 2) * 64 + a] = pack_f16x2(eh0, eh1);
                S[(2 * m + 3) * 64 + a] = pack_f16x2(RCPF(eh0), RCPF(eh1));
            }
        } else {
            const float* gp0 = (const float*)atoms_v + (size_t)(rowBase + 2 * a) * P_PRED + c0;
            float4 u0 = *(const float4*)gp0;
            float4 u1 = *(const float4*)(gp0 + 4);
            float4 d0 = *(const float4*)(gp0 + P_PRED);
            float4 d1 = *(const float4*)(gp0 + P_PRED + 4);
            float r0[8] = {u0.x, u0.y, u0.z, u0.w, u1.x, u1.y, u1.z, u1.w};
            float r1[8] = {d0.x, d0.y, d0.z, d0.w, d1.x, d1.y, d1.z, d1.w};
#pragma unroll
            for (int k = 0; k < 8; ++k) {
                float e0 = EXP2F(r0[k] * LOG2E);
                float e1 = EXP2F(r1[k] * LOG2E);
                const int m = c0 + k;
                S[(2 * m)     * 64 + a] = pack_f16x2(e0, e1);
                S[(2 * m + 1) * 64 + a] = pack_f16x2(RCPF(e0), RCPF(e1));
            }
        }
    }
    __syncthreads();

    // ======== phase 2: record loop (packed fp16) ========
    const int q2 = 2 * lane;                     // u16 row index of this row pair
    const char* E2c = (const char*)S + lane * 4; // per-lane E2 base (byte)
    float2 acc[8];
    int j = g * GCAP;                            // stream cursor

#pragma unroll
    for (int pp = 0; pp < 8; ++pp) {
        const int p = g * 8 + pp;                        // wave-uniform
        const u32 epp2 = S[(2 * p)     * 64 + lane];     // packed half2 rows
        const u32 epn2 = S[(2 * p + 1) * 64 + lane];
        const int n = (int)cnt8[p];
        __half2 a0 = u2h(0u);
        __half2 a1 = u2h(0u);

#define REC_BODY(J, A)                                                        \
        {                                                                     \
            const uint2 rec = srec[J];                 /* b64 broadcast */    \
            const u32 v1 = *(const u32*)(E2c + (rec.x & 0x7F00u));            \
            const u32 v2 = *(const u32*)(E2c + ((rec.x >> 8) & 0x7F00u));     \
            const u32 ssu = (rec.x & 1u) ? epn2 : epp2;                       \
            const __half2 D = __hadd2(u2h(ssu), __hadd2(u2h(v1), u2h(v2)));   \
            const __half2 r = h2rcp(D);                                       \
            A = __hfma2(__hmul2(u2h(ssu), r), u2h(rec.y), A);                 \
        }

        int e = 0;
        for (; e + 3 < n; e += 4) {        // unroll x4, dual accumulators
            REC_BODY(j,     a0)
            REC_BODY(j + 1, a1)
            REC_BODY(j + 2, a0)
            REC_BODY(j + 3, a1)
            j += 4;
        }
        for (; e < n; ++e, ++j) REC_BODY(j, a0)
#undef REC_BODY
        // combine dual accumulators in f32 (lo = row q2, hi = row q2+1)
        acc[pp] = make_float2(__low2float(a0)  + __low2float(a1),
                              __high2float(a0) + __high2float(a1));
    }

    // ======== phase 3: direct stores (R9 epilogue) ========
    if (bf16m) {
        u16* op0 = (u16*)out_v + (size_t)(rowBase + q2) * P_PRED + g * 8;
        u16* op1 = op0 + P_PRED;
        uint4 o0, o1v;
        o0.x  = pack_bf16x2(acc[0].x, acc[1].x);
        o0.y  = pack_bf16x2(acc[2].x, acc[3].x);
        o0.z  = pack_bf16x2(acc[4].x, acc[5].x);
        o0.w  = pack_bf16x2(acc[6].x, acc[7].x);
        o1v.x = pack_bf16x2(acc[0].y, acc[1].y);
        o1v.y = pack_bf16x2(acc[2].y, acc[3].y);
        o1v.z = pack_bf16x2(acc[4].y, acc[5].y);
        o1v.w = pack_bf16x2(acc[6].y, acc[7].y);
        *(uint4*)op0 = o0;
        *(uint4*)op1 = o1v;
    } else {
        float* op0 = (float*)out_v + (size_t)(rowBase + q2) * P_PRED + g * 8;
        float* op1 = op0 + P_PRED;
        *(float4*)(op0)     = make_float4(acc[0].x, acc[1].x, acc[2].x, acc[3].x);
        *(float4*)(op0 + 4) = make_float4(acc[4].x, acc[5].x, acc[6].x, acc[7].x);
        *(float4*)(op1)     = make_float4(acc[0].y, acc[1].y, acc[2].y, acc[3].y);
        *(float4*)(op1 + 4) = make_float4(acc[4].y, acc[5].y, acc[6].y, acc[7].y);
    }
}

extern "C" void kernel_launch(void* const* d_in, const int* in_sizes, int n_in,
                              void* d_out, int out_size, void* d_ws, size_t ws_size,
                              hipStream_t stream_h) {
    const u32* clause_weights = (const u32*)d_in[1]; // bf16 or f32 [128]
    const u32* literal_idx    = (const u32*)d_in[2]; // int32 or int64 [128,3]
    const u32* sign_bits      = (const u32*)d_in[3]; // int32 or int64 [128,3]
    (void)d_ws; (void)ws_size;                       // workspace unused

    ke_fp16<<<B_ROWS / RPB, TPB, 0, stream_h>>>(literal_idx, sign_bits,
                                                clause_weights, d_in[0],
                                                d_out);
}

// Round 9
// 98.085 us; speedup vs baseline: 3.9891x; 1.0368x over previous
//
#include <hip/hip_runtime.h>
#include <hip/hip_fp16.h>
#include <stdint.h>

typedef unsigned int  u32;
typedef unsigned short u16;

#define B_ROWS 131072
#define P_PRED 64
#define C_CLS  128
#define NPAIR  384               // C*L raw words for dtype detection
#define CAP    32                // max records per predicate (mean 6)
#define RPB    128               // rows per block (2 rows per thread)
#define TPB    512               // 8 waves; wave g owns predicates [8g, 8g+8)
#define GCAP   104               // record capacity per 8-pred group (mean 48)
#define LOG2E  1.4426950408889634f

#if __has_builtin(__builtin_amdgcn_exp2f)
#define EXP2F(x) __builtin_amdgcn_exp2f(x)
#else
#define EXP2F(x) exp2f(x)
#endif

#if __has_builtin(__builtin_amdgcn_rcpf)
#define RCPF(x) __builtin_amdgcn_rcpf(x)
#else
#define RCPF(x) (1.0f / (x))
#endif

__device__ __forceinline__ float bf16_to_f(u16 u) {
    return __uint_as_float(((u32)u) << 16);
}
__device__ __forceinline__ u16 f_to_bf16(float f) {
    u32 u = __float_as_uint(f);
    u += 0x7FFFu + ((u >> 16) & 1u);   // RNE
    return (u16)(u >> 16);
}
__device__ __forceinline__ u32 pack_bf16x2(float lo, float hi) {
    return (u32)f_to_bf16(lo) | ((u32)f_to_bf16(hi) << 16);
}
// fp16 pair helpers (u32 <-> __half2 bitcasts)
__device__ __forceinline__ u32 h2u(__half2 h) { union { __half2 h; u32 u; } v; v.h = h; return v.u; }
__device__ __forceinline__ __half2 u2h(u32 u) { union { __half2 h; u32 u; } v; v.u = u; return v.h; }
__device__ __forceinline__ u32 pack_f16x2(float lo, float hi) {
    return h2u(__floats2half2_rn(lo, hi));     // RN: 2x v_cvt_f16_f32 + pack
}

// ---------------------------------------------------------------------------
// R19 = R18 RESUBMIT (previous round's bench died with "MI355X container
// failed twice" — infrastructure, no kernel signal; code re-audited for OOB/
// race and found clean, so resubmitting unchanged per theory-first rules).
//
// R18: R17 (single-pass fp16, 4 blocks/CU, zero post-staging barriers in the
// record loop) + IN-PLACE per-clause reciprocal table.
//   Phase 1b (new, +2 barriers total): R[c][row] = h2rcp(e1+e2+e3) for all
//   128 clauses, computed into 16 VGPR temps (E2 reads complete), barrier,
//   written OVER E2 (R table = 32 KB = E2's exact footprint; E2 is dead
//   afterwards because the record loop's self values are preloaded into
//   registers). LDS stays 39 KB -> 4 blocks/CU (the R12-R16 WR attempts
//   paid 2x occupancy or per-round barriers for this same sharing; here
//   it is structurally free).
//   Record loop collapses to: srec b64 + R b32 + cndmask (self select via
//   the pre-signed weight's sign bit) + v_pk_mul + v_pk_fma = ~5 VALU +
//   2 DS per record (R17: ~10 VALU + 3 DS, incl. 2 rcp + 2 add).
//   Arithmetic bit-identical to R17 (same D/rcp/mul order, computed once
//   per clause instead of 3x).
// Workspace d_ws: UNUSED.
// ---------------------------------------------------------------------------
__global__ __launch_bounds__(TPB, 8)
void ke_rtab(const u32* __restrict__ lidx_w,
             const u32* __restrict__ sb_w,
             const u32* __restrict__ w_w,
             const void* __restrict__ atoms_v,
             void* __restrict__ out_v) {
    __shared__ u32 S[8192];                   // 32 KB: prep scratch -> E2 -> R
    __shared__ uint2 srec[8 * GCAP];          // 6656 B (persists all phases)
    __shared__ unsigned char cnt8[P_PRED];    // 64 B
    __shared__ u32 cslotS[C_CLS];             // 512 B clause slot triples

    const int tid = threadIdx.x;
    const int lane = tid & 63;
    const int g = __builtin_amdgcn_readfirstlane(tid >> 6);  // 0..7, SGPR
    const int rowBase = blockIdx.x * RPB;

    // ======== phase 0: inline prep (scratch aliased into S) ========
    int*   scnt  = (int*)&S[0];       // [64]
    int*   det   = (int*)&S[64];      // [3]
    int*   sidx  = (int*)&S[128];     // [384]
    int*   ssb   = (int*)&S[512];     // [384]
    u32*   recPk = &S[1024];          // [64][32]
    u32*   recWH = &S[3072];          // [64][32] pre-signed half2-dup weight

    if (tid < P_PRED) scnt[tid] = 0;
    if (tid < 3) det[tid] = 1;
    __syncthreads();
    if (tid < NPAIR / 2) {
        if (lidx_w[2 * tid + 1] != 0u) det[0] = 0;   // benign race (all write 0)
        if (sb_w[2 * tid + 1]   != 0u) det[1] = 0;
    }
    if (tid == 0 && (w_w[0] & 0xFFFFu) == 0u) det[2] = 0;
    __syncthreads();
    if (tid < NPAIR) {
        sidx[tid] = (int)(det[0] ? lidx_w[2 * tid] : lidx_w[tid]);
        ssb[tid]  = (int)(det[1] ? sb_w[2 * tid]   : sb_w[tid]);
    }
    __syncthreads();
    const bool bf16m = (det[2] != 0);            // latch before S is reused
    if (tid < NPAIR) {
        const int c = tid / 3;
        const int p = sidx[tid];
        const int slot = atomicAdd(&scnt[p], 1); // prep-only LDS atomics: fine
        float wraw = bf16m ? bf16_to_f((u16)(w_w[c / 2] >> ((c & 1) * 16)))
                           : __uint_as_float(w_w[c]);
        float wc = fminf(fmaxf(wraw, 0.0f), 500.0f);
        if (slot < CAP) {
            recPk[p * CAP + slot] = (u32)c << 8;          // R-table byte offset
            u32 wh2 = pack_f16x2(wc, wc);                 // duplicated half2
            if (!ssb[tid]) wh2 ^= 0x80008000u;            // pre-signed (sign bit
            recWH[p * CAP + slot] = wh2;                  //  also keys self-select)
        }
    }
    if (tid < C_CLS) {
        const int c = tid;
        const u32 s0 = 2u * (u32)sidx[3 * c]     + (ssb[3 * c]     ? 0u : 1u);
        const u32 s1 = 2u * (u32)sidx[3 * c + 1] + (ssb[3 * c + 1] ? 0u : 1u);
        const u32 s2 = 2u * (u32)sidx[3 * c + 2] + (ssb[3 * c + 2] ? 0u : 1u);
        cslotS[c] = s0 | (s1 << 8) | (s2 << 16);
    }
    __syncthreads();
    if (tid < P_PRED) {
        const int p = tid;
        const int gg = p >> 3;
        const int n = min(scnt[p], CAP);
        int off = 0;
        for (int pb = gg * 8; pb < p; ++pb) off += min(scnt[pb], CAP);
        int ncl = 0;
        for (int j = 0; j < n; ++j) {
            if (off + j < GCAP) {
                srec[gg * GCAP + off + j] =
                    make_uint2(recPk[p * CAP + j], recWH[p * CAP + j]);
                ++ncl;
            }
        }
        cnt8[p] = (unsigned char)ncl;
    }
    __syncthreads();   // srec/cnt8 ready; prep scratch in S now dead

    // ======== phase 1: stage E2 as half2 (paired-row b32 writes) ========
    {
        const int a = tid & 63;                  // row pair (2a, 2a+1)
        const int c0 = (tid >> 6) * 8;           // 8-atom chunk
        if (bf16m) {
            const u16* gp0 = (const u16*)atoms_v + (size_t)(rowBase + 2 * a) * P_PRED + c0;
            uint4 v0 = *(const uint4*)gp0;            // row 2a
            uint4 v1 = *(const uint4*)(gp0 + P_PRED); // row 2a+1
            u32 w0[4] = {v0.x, v0.y, v0.z, v0.w};
            u32 w1[4] = {v1.x, v1.y, v1.z, v1.w};
#pragma unroll
            for (int k = 0; k < 4; ++k) {
                float xl0 = __uint_as_float(w0[k] << 16) * LOG2E;
                float xh0 = __uint_as_float(w0[k] & 0xFFFF0000u) * LOG2E;
                float xl1 = __uint_as_float(w1[k] << 16) * LOG2E;
                float xh1 = __uint_as_float(w1[k] & 0xFFFF0000u) * LOG2E;
                float el0 = EXP2F(xl0), eh0 = EXP2F(xh0);
                float el1 = EXP2F(xl1), eh1 = EXP2F(xh1);
                const int m = c0 + 2 * k;
                S[(2 * m)     * 64 + a] = pack_f16x2(el0, el1);
                S[(2 * m + 1) * 64 + a] = pack_f16x2(RCPF(el0), RCPF(el1));
                S[(2 * m + 2) * 64 + a] = pack_f16x2(eh0, eh1);
                S[(2 * m + 3) * 64 + a] = pack_f16x2(RCPF(eh0), RCPF(eh1));
            }
        } else {
            const float* gp0 = (const float*)atoms_v + (size_t)(rowBase + 2 * a) * P_PRED + c0;
            float4 u0 = *(const float4*)gp0;
            float4 u1 = *(const float4*)(gp0 + 4);
            float4 d0 = *(const float4*)(gp0 + P_PRED);
            float4 d1 = *(const float4*)(gp0 + P_PRED + 4);
            float r0[8] = {u0.x, u0.y, u0.z, u0.w, u1.x, u1.y, u1.z, u1.w};
            float r1[8] = {d0.x, d0.y, d0.z, d0.w, d1.x, d1.y, d1.z, d1.w};
#pragma unroll
            for (int k = 0; k < 8; ++k) {
                float e0 = EXP2F(r0[k] * LOG2E);
                float e1 = EXP2F(r1[k] * LOG2E);
                const int m = c0 + k;
                S[(2 * m)     * 64 + a] = pack_f16x2(e0, e1);
                S[(2 * m + 1) * 64 + a] = pack_f16x2(RCPF(e0), RCPF(e1));
            }
        }
    }
    __syncthreads();

    // ======== phase 1b: self preload + in-place R table ========
    // Self values (wave g's preds -> slots 16g..16g+15) preloaded to regs
    // BEFORE the overwrite. R[c] lives at slot index c (byte c<<8) of S.
    u32 selfP[8], selfN[8];
#pragma unroll
    for (int pp = 0; pp < 8; ++pp) {
        selfP[pp] = S[(16 * g + 2 * pp)     * 64 + lane];
        selfN[pp] = S[(16 * g + 2 * pp + 1) * 64 + lane];
    }
    u32 rt[16];
#pragma unroll
    for (int k = 0; k < 16; ++k) {
        const int c  = g * 16 + k;                 // wave-uniform clause
        const u32 cs = cslotS[c];                  // broadcast LDS read
        const u32 e0 = S[((cs      ) & 255u) * 64 + lane];
        const u32 e1 = S[((cs >>  8) & 255u) * 64 + lane];
        const u32 e2 = S[((cs >> 16) & 255u) * 64 + lane];
        const __half2 D = __hadd2(u2h(e0), __hadd2(u2h(e1), u2h(e2)));
        rt[k] = h2u(h2rcp(D));
    }
    __syncthreads();       // ALL E2 reads complete (incl. other waves')
#pragma unroll
    for (int k = 0; k < 16; ++k) S[(g * 16 + k) * 64 + lane] = rt[k];
    __syncthreads();       // R table ready

    // ======== phase 2: record loop (R-table fast path) ========
    const int q2 = 2 * lane;                     // u16 row index of this row pair
    const char* Rc = (const char*)S + lane * 4;  // per-lane R base (byte)
    float2 acc[8];
    int j = g * GCAP;                            // stream cursor

#pragma unroll
    for (int pp = 0; pp < 8; ++pp) {
        const int n = (int)cnt8[pp + g * 8];
        const u32 sp = selfP[pp], sn = selfN[pp];
        __half2 a0 = u2h(0u);
        __half2 a1 = u2h(0u);

#define REC_BODY(J, A)                                                        \
        {                                                                     \
            const uint2 rec = srec[J];                 /* b64 broadcast */    \
            const u32 Rv  = *(const u32*)(Rc + (rec.x & 0x7F00u));            \
            const u32 ssu = ((int)rec.y < 0) ? sn : sp;  /* sign keys self */ \
            A = __hfma2(__hmul2(u2h(ssu), u2h(Rv)), u2h(rec.y), A);           \
        }

        int e = 0;
        for (; e + 3 < n; e += 4) {        // unroll x4, dual accumulators
            REC_BODY(j,     a0)
            REC_BODY(j + 1, a1)
            REC_BODY(j + 2, a0)
            REC_BODY(j + 3, a1)
            j += 4;
        }
        for (; e < n; ++e, ++j) REC_BODY(j, a0)
#undef REC_BODY
        // combine dual accumulators in f32 (lo = row q2, hi = row q2+1)
        acc[pp] = make_float2(__low2float(a0)  + __low2float(a1),
                              __high2float(a0) + __high2float(a1));
    }

    // ======== phase 3: direct stores (R9 epilogue) ========
    if (bf16m) {
        u16* op0 = (u16*)out_v + (size_t)(rowBase + q2) * P_PRED + g * 8;
        u16* op1 = op0 + P_PRED;
        uint4 o0, o1v;
        o0.x  = pack_bf16x2(acc[0].x, acc[1].x);
        o0.y  = pack_bf16x2(acc[2].x, acc[3].x);
        o0.z  = pack_bf16x2(acc[4].x, acc[5].x);
        o0.w  = pack_bf16x2(acc[6].x, acc[7].x);
        o1v.x = pack_bf16x2(acc[0].y, acc[1].y);
        o1v.y = pack_bf16x2(acc[2].y, acc[3].y);
        o1v.z = pack_bf16x2(acc[4].y, acc[5].y);
        o1v.w = pack_bf16x2(acc[6].y, acc[7].y);
        *(uint4*)op0 = o0;
        *(uint4*)op1 = o1v;
    } else {
        float* op0 = (float*)out_v + (size_t)(rowBase + q2) * P_PRED + g * 8;
        float* op1 = op0 + P_PRED;
        *(float4*)(op0)     = make_float4(acc[0].x, acc[1].x, acc[2].x, acc[3].x);
        *(float4*)(op0 + 4) = make_float4(acc[4].x, acc[5].x, acc[6].x, acc[7].x);
        *(float4*)(op1)     = make_float4(acc[0].y, acc[1].y, acc[2].y, acc[3].y);
        *(float4*)(op1 + 4) = make_float4(acc[4].y, acc[5].y, acc[6].y, acc[7].y);
    }
}

extern "C" void kernel_launch(void* const* d_in, const int* in_sizes, int n_in,
                              void* d_out, int out_size, void* d_ws, size_t ws_size,
                              hipStream_t stream_h) {
    const u32* clause_weights = (const u32*)d_in[1]; // bf16 or f32 [128]
    const u32* literal_idx    = (const u32*)d_in[2]; // int32 or int64 [128,3]
    const u32* sign_bits      = (const u32*)d_in[3]; // int32 or int64 [128,3]
    (void)d_ws; (void)ws_size;                       // workspace unused

    ke_rtab<<<B_ROWS / RPB, TPB, 0, stream_h>>>(literal_idx, sign_bits,
                                                clause_weights, d_in[0],
                                                d_out);
}